// Round 9
// baseline (513.139 us; speedup 1.0000x reference)
//
#include <hip/hip_runtime.h>
#include <hip/hip_bf16.h>

// TalkingHeads: BS=2, C_IN=512, SEQ=1024, DK=DV=64, H=16. fp32 I/O.
// Round 9: kill the opart/lpart scratch spill. gfx950 unified VGPR/AGPR file:
// r8's launch_bounds(256,2) let the compiler cap at 128 total regs while the
// live set (el 64 + oacc 64 + jc 32 + frags) needs ~175 -> 125MB/round spill
// traffic (the measured FETCH/WRITE 160MB). Fix: launch_bounds(256,1) to allow
// ~192 regs (still 2 waves/SIMD) + fold J per HEAD-PAIR (transient c0,c1
// instead of jc8[8]) to cut peak by ~24 regs. Dataflow otherwise = r8.

#define B_S  2
#define C_INN 512
#define SEQL 1024
#define D_K  64
#define N_H  16
#define BQJ  (2 * 1024 * 1024)   // elements of one O partial [b][q][j]
#define KSL  16                  // lpart grid split (x4 waves -> 64 chunks)
#define KSO  8                   // opart split

typedef __attribute__((ext_vector_type(4))) float floatx4;
typedef __attribute__((ext_vector_type(8))) short short8;
typedef __attribute__((ext_vector_type(2))) unsigned int uint2v;

static __device__ __forceinline__ float bf2f(unsigned short u) {
  union { unsigned int i; float f; } x; x.i = ((unsigned int)u) << 16; return x.f;
}
static __device__ __forceinline__ unsigned short f2bf(float f) {
  union { float f; unsigned int i; } x; x.f = f;
  return (unsigned short)((x.i + 0x7fffu + ((x.i >> 16) & 1u)) >> 16);
}
static __device__ __forceinline__ unsigned int pkbf(float a, float b) {
  return (unsigned int)f2bf(a) | ((unsigned int)f2bf(b) << 16);
}

// ---------------------------------------------------------------------------
// Kernel 1: QKV projection (fp32 in, bf16 out).
// Q,K -> [b][h][s][d] ; V -> [b][v][d][s].
// ---------------------------------------------------------------------------
__global__ __launch_bounds__(256) void ath_qkv(
    const float* __restrict__ inp,
    const float* __restrict__ Wq,
    const float* __restrict__ Wk,
    const float* __restrict__ Wv,
    const float* __restrict__ Aq,
    const float* __restrict__ Ak,
    const float* __restrict__ Av,
    unsigned short* __restrict__ ws)
{
  const int sblk = blockIdx.x;
  const int nblk = blockIdx.y;
  const int z = blockIdx.z;
  const int b = z / 3, p = z % 3;
  const float* W  = (p == 0) ? Wq : ((p == 1) ? Wk : Wv);
  const float* Ap = (p == 0) ? Aq : ((p == 1) ? Ak : Av);
  const float sig = 1.0f / (1.0f + __expf(-Ap[0]));

  __shared__ __align__(16) unsigned short As[64][40];
  __shared__ __align__(16) unsigned short Bs[64][40];

  const int tid = threadIdx.x;
  const int w = tid >> 6, lane = tid & 63;
  const int l15 = lane & 15, quad = lane >> 4;

  floatx4 acc[4];
#pragma unroll
  for (int i = 0; i < 4; ++i) acc[i] = (floatx4){0.f, 0.f, 0.f, 0.f};

  for (int cc = 0; cc < 16; ++cc) {
    const int c0 = cc * 32;
    __syncthreads();
#pragma unroll
    for (int t = 0; t < 2; ++t) {
      const int i = tid * 2 + t;
      const int c = i >> 4, sq = i & 15;
      const floatx4 g = *(const floatx4*)(inp + ((size_t)(b * C_INN + c0 + c) * SEQL + sblk * 64 + sq * 4));
      As[sq * 4 + 0][c] = f2bf(g[0]); As[sq * 4 + 1][c] = f2bf(g[1]);
      As[sq * 4 + 2][c] = f2bf(g[2]); As[sq * 4 + 3][c] = f2bf(g[3]);
    }
#pragma unroll
    for (int t = 0; t < 2; ++t) {
      const int i = tid * 2 + t;
      const int c = i >> 4, nq = i & 15;
      const floatx4 g = *(const floatx4*)(W + ((size_t)(c0 + c) * 1024 + nblk * 64 + nq * 4));
      Bs[nq * 4 + 0][c] = f2bf(g[0]); Bs[nq * 4 + 1][c] = f2bf(g[1]);
      Bs[nq * 4 + 2][c] = f2bf(g[2]); Bs[nq * 4 + 3][c] = f2bf(g[3]);
    }
    __syncthreads();
    const short8 a = *(const short8*)&As[w * 16 + l15][quad * 8];
#pragma unroll
    for (int nt = 0; nt < 4; ++nt) {
      const short8 bb = *(const short8*)&Bs[nt * 16 + l15][quad * 8];
      acc[nt] = __builtin_amdgcn_mfma_f32_16x16x32_bf16(a, bb, acc[nt], 0, 0, 0);
    }
  }

  unsigned short* out = ws + (size_t)p * ((size_t)B_S * N_H * SEQL * D_K);
#pragma unroll
  for (int nt = 0; nt < 4; ++nt) {
    const int h = l15;
    const int d = nblk * 4 + nt;
#pragma unroll
    for (int r = 0; r < 4; ++r) {
      const int s = sblk * 64 + w * 16 + quad * 4 + r;
      const float vout = acc[nt][r] * sig;
      if (p == 2) out[((size_t)((b * N_H + h) * D_K + d)) * SEQL + s] = f2bf(vout);
      else        out[((size_t)((b * N_H + h) * SEQL + s)) * D_K + d] = f2bf(vout);
    }
  }
}

// ---------------------------------------------------------------------------
// K2a: partial l. grid(64 qblk, KSL, 2 b); wave w handles 16-k tile ks*64+w*16.
// J^T folded into el per head-pair (low register pressure, no spill).
// ---------------------------------------------------------------------------
__global__ __launch_bounds__(256, 1) void ath_lpart(
    const float* __restrict__ maskp,
    const float* __restrict__ Wl,
    const unsigned short* __restrict__ qkv,
    float* __restrict__ lp)
{
  const int qblk = blockIdx.x;
  const int ks   = blockIdx.y;
  const int b    = blockIdx.z;
  const int tid = threadIdx.x;
  const int w = tid >> 6, lane = tid & 63;
  const int l15 = lane & 15, quad = lane >> 4;

  const unsigned short* Qf = qkv;
  const unsigned short* Kf = qkv + (size_t)B_S * N_H * SEQL * D_K;

  const int kabs0 = ks * 64 + w * 16;

  floatx4 el[16];
  {
    floatx4 mk;
#pragma unroll
    for (int r = 0; r < 4; ++r) mk[r] = -maskp[b * SEQL + kabs0 + quad * 4 + r];
#pragma unroll
    for (int g = 0; g < 16; ++g) el[g] = mk;
  }

#pragma unroll
  for (int hp = 0; hp < 8; ++hp) {
    floatx4 c0, c1;
#pragma unroll
    for (int u = 0; u < 2; ++u) {
      const int h = hp * 2 + u;
      const unsigned short* qb = Qf + ((size_t)((b * N_H + h) * SEQL) + qblk * 16 + l15) * D_K;
      const unsigned short* kb = Kf + ((size_t)((b * N_H + h) * SEQL) + kabs0 + l15) * D_K;
      const short8 q0 = *(const short8*)(qb + quad * 8);
      const short8 q1 = *(const short8*)(qb + 32 + quad * 8);
      const short8 k0 = *(const short8*)(kb + quad * 8);
      const short8 k1 = *(const short8*)(kb + 32 + quad * 8);
      floatx4 c = (floatx4){0.f, 0.f, 0.f, 0.f};
      c = __builtin_amdgcn_mfma_f32_16x16x32_bf16(k0, q0, c, 0, 0, 0);  // A=K -> rows k
      c = __builtin_amdgcn_mfma_f32_16x16x32_bf16(k1, q1, c, 0, 0, 0);
      if (u == 0) c0 = c; else c1 = c;
    }
#pragma unroll
    for (int g = 0; g < 16; ++g) {
      const float w0 = Wl[(hp * 2) * 16 + g];      // wave-uniform -> s_load
      const float w1 = Wl[(hp * 2 + 1) * 16 + g];
      floatx4 e = el[g];
#pragma unroll
      for (int r = 0; r < 4; ++r) e[r] += c0[r] * w0 + c1[r] * w1;
      el[g] = e;
    }
  }

  float lac[16];
#pragma unroll
  for (int g = 0; g < 16; ++g) {
    lac[g] = __expf(fminf(fmaxf(el[g][0], -60.f), 60.f))
           + __expf(fminf(fmaxf(el[g][1], -60.f), 60.f))
           + __expf(fminf(fmaxf(el[g][2], -60.f), 60.f))
           + __expf(fminf(fmaxf(el[g][3], -60.f), 60.f));
  }

  // reduce across the 4 quads (same l15)
#pragma unroll
  for (int g = 0; g < 16; ++g) {
    float v = lac[g];
    v += __shfl_xor(v, 16);
    v += __shfl_xor(v, 32);
    lac[g] = v;
  }
  if (quad == 0) {
    const int kse = ks * 4 + w;
    float* dst = lp + ((size_t)((kse * 2 + b) * SEQL + qblk * 16 + l15)) * 16;
#pragma unroll
    for (int g4 = 0; g4 < 4; ++g4)
      *(floatx4*)(dst + g4 * 4) = (floatx4){lac[g4 * 4], lac[g4 * 4 + 1], lac[g4 * 4 + 2], lac[g4 * 4 + 3]};
  }
}

// ---------------------------------------------------------------------------
// K2r: invl = 1 / sum_{kse<64} lp. grid(128, 256 thr).
// ---------------------------------------------------------------------------
__global__ __launch_bounds__(256) void ath_linv(
    const float* __restrict__ lp, float* __restrict__ invl)
{
  const int t = blockIdx.x * 256 + threadIdx.x;
  const int b = t >> 14, rem = t & 16383;
  float s = 0.f;
  for (int kse = 0; kse < 64; ++kse) s += lp[(size_t)((kse * 2 + b)) * 16384 + rem];
  invl[t] = 1.0f / fmaxf(s, 1e-37f);
}

// ---------------------------------------------------------------------------
// K2b: partial O. grid(64 qblk, KSO, 2 b). kchunk=128 -> 2 rounds of 64 k
// (wave w owns 16-k tile w). J folded into el per head-pair; exp/invl in
// place; U mix (SGPR weights) -> padded LDS v-exchange; V-phase bf16 MFMA.
// ---------------------------------------------------------------------------
__global__ __launch_bounds__(256, 1) void ath_opart(
    const float* __restrict__ maskp,
    const float* __restrict__ Wl,
    const float* __restrict__ Ww,
    const unsigned short* __restrict__ qkv,
    const float* __restrict__ invl,
    unsigned short* __restrict__ Obp)
{
  const int qblk = blockIdx.x;
  const int ks   = blockIdx.y;
  const int b    = blockIdx.z;
  const int tid = threadIdx.x;
  const int w = tid >> 6, lane = tid & 63;
  const int l15 = lane & 15, quad = lane >> 4;

  const unsigned short* Qf = qkv;
  const unsigned short* Kf = qkv + (size_t)B_S * N_H * SEQL * D_K;
  const unsigned short* Vf = qkv + 2 * (size_t)B_S * N_H * SEQL * D_K;

  // Us: b64 slots [tile4][v16][qw4][q16 +1pad] -> 4*16*4*17 * 8B = 34.8KB
  __shared__ __align__(16) unsigned int UsU[4 * 16 * 4 * 17 * 2];
  __shared__ float invls[16][16];
  uint2v* Us2 = (uint2v*)UsU;

  invls[tid >> 4][tid & 15] =
      invl[(size_t)b * 16384 + (qblk * 16 + (tid >> 4)) * 16 + (tid & 15)];

  floatx4 oacc[4][4];
#pragma unroll
  for (int a = 0; a < 4; ++a)
#pragma unroll
    for (int d = 0; d < 4; ++d) oacc[a][d] = (floatx4){0.f, 0.f, 0.f, 0.f};

  __syncthreads();  // invls visible

  for (int rd = 0; rd < 2; ++rd) {
    const int kabs0 = ks * 128 + rd * 64 + w * 16;

    // ---- EL accumulator; fold head-pairs as their J^T lands ----
    floatx4 el[16];
    {
      floatx4 mk;
#pragma unroll
      for (int r = 0; r < 4; ++r) mk[r] = -maskp[b * SEQL + kabs0 + quad * 4 + r];
#pragma unroll
      for (int g = 0; g < 16; ++g) el[g] = mk;
    }

#pragma unroll
    for (int hp = 0; hp < 8; ++hp) {
      floatx4 c0, c1;
#pragma unroll
      for (int u = 0; u < 2; ++u) {
        const int h = hp * 2 + u;
        const unsigned short* qb = Qf + ((size_t)((b * N_H + h) * SEQL) + qblk * 16 + l15) * D_K;
        const unsigned short* kb = Kf + ((size_t)((b * N_H + h) * SEQL) + kabs0 + l15) * D_K;
        const short8 q0 = *(const short8*)(qb + quad * 8);
        const short8 q1 = *(const short8*)(qb + 32 + quad * 8);
        const short8 k0 = *(const short8*)(kb + quad * 8);
        const short8 k1 = *(const short8*)(kb + 32 + quad * 8);
        floatx4 c = (floatx4){0.f, 0.f, 0.f, 0.f};
        c = __builtin_amdgcn_mfma_f32_16x16x32_bf16(k0, q0, c, 0, 0, 0);
        c = __builtin_amdgcn_mfma_f32_16x16x32_bf16(k1, q1, c, 0, 0, 0);
        if (u == 0) c0 = c; else c1 = c;
      }
#pragma unroll
      for (int g = 0; g < 16; ++g) {
        const float w0 = Wl[(hp * 2) * 16 + g];
        const float w1 = Wl[(hp * 2 + 1) * 16 + g];
        floatx4 e = el[g];
#pragma unroll
        for (int r = 0; r < 4; ++r) e[r] += c0[r] * w0 + c1[r] * w1;
        el[g] = e;
      }
    }

    // ---- softmax scale in place: el := exp(clamp(el)) * invl ----
#pragma unroll
    for (int g = 0; g < 16; ++g) {
      const float iv = invls[l15][g];
      floatx4 e = el[g];
#pragma unroll
      for (int r = 0; r < 4; ++r)
        e[r] = __expf(fminf(fmaxf(e[r], -60.f), 60.f)) * iv;
      el[g] = e;
    }

    // ---- U mix (Ww scalar-uniform) -> Us exchange ----
#pragma unroll
    for (int v = 0; v < 16; ++v) {
      float u0 = 0.f, u1 = 0.f, u2 = 0.f, u3 = 0.f;
#pragma unroll
      for (int g = 0; g < 16; ++g) {
        const float wv = Ww[g * 16 + v];
        u0 += el[g][0] * wv; u1 += el[g][1] * wv;
        u2 += el[g][2] * wv; u3 += el[g][3] * wv;
      }
      Us2[((w * 16 + v) * 4 + quad) * 17 + l15] = (uint2v){pkbf(u0, u1), pkbf(u2, u3)};
    }

    __syncthreads();  // all waves' U ready

    // ---- V-phase: wave w -> v = 4w..4w+3, two K=32 MFMAs cover 64 k ----
#pragma unroll
    for (int tp = 0; tp < 2; ++tp) {
      const int t = tp * 2 + (quad >> 1);
      const int qwb = (quad & 1) * 2;
      const int kt_abs = ks * 128 + rd * 64 + tp * 32;
#pragma unroll
      for (int vv = 0; vv < 4; ++vv) {
        const int v = w * 4 + vv;
        const int i1 = ((t * 16 + v) * 4 + qwb) * 17 + l15;
        union { uint2v a[2]; short8 s; } ux;
        ux.a[0] = Us2[i1];
        ux.a[1] = Us2[i1 + 17];
#pragma unroll
        for (int dt = 0; dt < 4; ++dt) {
          const short8 vfr = *(const short8*)(Vf +
              ((size_t)((b * N_H + v) * D_K + dt * 16 + l15)) * SEQL + kt_abs + quad * 8);
          oacc[vv][dt] = __builtin_amdgcn_mfma_f32_16x16x32_bf16(ux.s, vfr, oacc[vv][dt], 0, 0, 0);
        }
      }
    }

    __syncthreads();  // Us free for next round
  }

  // write partial O bf16: Obp[ks][b][q][d*16+v]
#pragma unroll
  for (int vv = 0; vv < 4; ++vv) {
    const int v = w * 4 + vv;
#pragma unroll
    for (int dt = 0; dt < 4; ++dt) {
      const int d = dt * 16 + l15;
#pragma unroll
      for (int r = 0; r < 4; ++r) {
        const int q = qblk * 16 + quad * 4 + r;
        Obp[(size_t)ks * BQJ + ((size_t)(b * SEQL + q)) * 1024 + d * 16 + v] = f2bf(oacc[vv][dt][r]);
      }
    }
  }
}

// ---------------------------------------------------------------------------
// K2s: Obsum = sum_ks Obp. grid(1024, 256 thr).
// ---------------------------------------------------------------------------
__global__ __launch_bounds__(256) void ath_osum(
    const unsigned short* __restrict__ Obp,
    unsigned short* __restrict__ Obsum)
{
  const size_t i = ((size_t)blockIdx.x * 256 + threadIdx.x) * 8;
  float a[8];
#pragma unroll
  for (int e = 0; e < 8; ++e) a[e] = 0.f;
#pragma unroll
  for (int ks = 0; ks < KSO; ++ks) {
    const short8 v = *(const short8*)(Obp + (size_t)ks * BQJ + i);
#pragma unroll
    for (int e = 0; e < 8; ++e) a[e] += bf2f((unsigned short)v[e]);
  }
  short8 o;
#pragma unroll
  for (int e = 0; e < 8; ++e) o[e] = (short)f2bf(a[e]);
  *(short8*)(Obsum + i) = o;
}

// ---------------------------------------------------------------------------
// Kernel 3: out[b][co][q] = inp + sum_j Obsum[b][q][j] * Wo[j][co]. fp32 out.
// ---------------------------------------------------------------------------
__global__ __launch_bounds__(256) void ath_out(
    const float* __restrict__ inp,
    const float* __restrict__ Wo,
    const unsigned short* __restrict__ Ob,
    float* __restrict__ out)
{
  const int qblk = blockIdx.x;
  const int cblk = blockIdx.y;
  const int b    = blockIdx.z;
  const int tid = threadIdx.x;
  const int w = tid >> 6, lane = tid & 63;
  const int l15 = lane & 15, quad = lane >> 4;

  __shared__ __align__(16) unsigned short Os[64][40];
  __shared__ __align__(16) unsigned short Wt[64][40];

  floatx4 acc[4];
#pragma unroll
  for (int i = 0; i < 4; ++i) acc[i] = (floatx4){0.f, 0.f, 0.f, 0.f};

  for (int jc = 0; jc < 32; ++jc) {
    const int j0 = jc * 32;
    __syncthreads();
    {
      const int q = tid >> 2, jq = tid & 3;
      const unsigned short* g = Ob + ((size_t)(b * SEQL + qblk * 64 + q)) * 1024 + j0 + jq * 8;
      *(short8*)&Os[q][jq * 8] = *(const short8*)g;
    }
#pragma unroll
    for (int t = 0; t < 2; ++t) {
      const int i = tid * 2 + t;
      const int j = i >> 4, cq = i & 15;
      const floatx4 g = *(const floatx4*)(Wo + ((size_t)(j0 + j) * 512 + cblk * 64 + cq * 4));
      Wt[cq * 4 + 0][j] = f2bf(g[0]); Wt[cq * 4 + 1][j] = f2bf(g[1]);
      Wt[cq * 4 + 2][j] = f2bf(g[2]); Wt[cq * 4 + 3][j] = f2bf(g[3]);
    }
    __syncthreads();
    const short8 a = *(const short8*)&Os[w * 16 + l15][quad * 8];
#pragma unroll
    for (int nt = 0; nt < 4; ++nt) {
      const short8 bb = *(const short8*)&Wt[nt * 16 + l15][quad * 8];
      acc[nt] = __builtin_amdgcn_mfma_f32_16x16x32_bf16(a, bb, acc[nt], 0, 0, 0);
    }
  }

#pragma unroll
  for (int nt = 0; nt < 4; ++nt) {
    const int co = cblk * 64 + nt * 16 + l15;
    const int qb = qblk * 64 + w * 16 + quad * 4;
    const float* ip = inp + ((size_t)(b * 512 + co)) * SEQL + qb;
    float* op = out + ((size_t)(b * 512 + co)) * SEQL + qb;
#pragma unroll
    for (int r = 0; r < 4; ++r) op[r] = acc[nt][r] + ip[r];
  }
}

// ---------------------------------------------------------------------------
extern "C" void kernel_launch(void* const* d_in, const int* in_sizes, int n_in,
                              void* d_out, int out_size, void* d_ws, size_t ws_size,
                              hipStream_t stream) {
  (void)in_sizes; (void)n_in; (void)out_size; (void)ws_size;
  const float* inp   = (const float*)d_in[0];
  const float* maskp = (const float*)d_in[1];
  const float* Wq    = (const float*)d_in[2];
  const float* Wk    = (const float*)d_in[3];
  const float* Wv    = (const float*)d_in[4];
  const float* Aq    = (const float*)d_in[5];
  const float* Ak    = (const float*)d_in[6];
  const float* Av    = (const float*)d_in[7];
  const float* Wl    = (const float*)d_in[8];
  const float* Ww    = (const float*)d_in[9];
  const float* Wo    = (const float*)d_in[10];

  const size_t MB = 1u << 20;
  unsigned short* qkv   = (unsigned short*)d_ws;                       // 12 MB bf16 Q,K,V
  unsigned short* Obsum = (unsigned short*)((char*)d_ws + 12 * MB);    // 4 MB bf16
  float*          invl  = (float*)((char*)d_ws + 16 * MB);             // 128 KB
  float*          lp    = (float*)((char*)d_ws + 18 * MB);             // 8 MB (dead before Obp use)
  unsigned short* Obp   = (unsigned short*)((char*)d_ws + 18 * MB);    // KSO*4 MB = 32 MB
  float* out = (float*)d_out;

  ath_qkv<<<dim3(16, 16, 6), 256, 0, stream>>>(inp, Wq, Wk, Wv, Aq, Ak, Av, qkv);
  ath_lpart<<<dim3(64, KSL, 2), 256, 0, stream>>>(maskp, Wl, qkv, lp);
  ath_linv<<<dim3(128), 256, 0, stream>>>(lp, invl);
  ath_opart<<<dim3(64, KSO, 2), 256, 0, stream>>>(maskp, Wl, Ww, qkv, invl, Obp);
  ath_osum<<<dim3(1024), 256, 0, stream>>>(Obp, Obsum);
  ath_out<<<dim3(16, 8, 2), 256, 0, stream>>>(inp, Wo, Obsum, out);
}

// Round 10
// 366.246 us; speedup vs baseline: 1.4011x; 1.4011x over previous
//
#include <hip/hip_runtime.h>
#include <hip/hip_bf16.h>

// TalkingHeads: BS=2, C_IN=512, SEQ=1024, DK=DV=64, H=16. fp32 I/O.
// Round 10: revert to round-6 structure (measured best: opart 116us, total 361)
// with the J-store bank-conflict fix: J computed as mfma(K,Q) so C rows=k,
// cols=q(lane l15) -> store ((quad*4+r)*16+l15)*9 hits 16 distinct banks
// (4-way from quads) instead of r6's 2-bank 8-way. All reads unchanged.

#define B_S  2
#define C_INN 512
#define SEQL 1024
#define D_K  64
#define N_H  16
#define BQJ  (2 * 1024 * 1024)   // elements of one O partial [b][q][j]
#define KSL  16                  // lpart split
#define KSO  8                   // opart split

typedef __attribute__((ext_vector_type(4))) float floatx4;
typedef __attribute__((ext_vector_type(8))) short short8;
typedef __fp16 h2raw __attribute__((ext_vector_type(2)));   // cvt_pkrtz return type
typedef _Float16 h2 __attribute__((ext_vector_type(2)));    // arithmetic type

static __device__ __forceinline__ float bf2f(unsigned short u) {
  union { unsigned int i; float f; } x; x.i = ((unsigned int)u) << 16; return x.f;
}
static __device__ __forceinline__ unsigned short f2bf(float f) {
  union { float f; unsigned int i; } x; x.f = f;
  return (unsigned short)((x.i + 0x7fffu + ((x.i >> 16) & 1u)) >> 16);
}
static __device__ __forceinline__ unsigned int pkh2(float a, float b) {
  h2raw r = __builtin_amdgcn_cvt_pkrtz(a, b);
  union { h2raw h; unsigned int u; } x; x.h = r; return x.u;
}
static __device__ __forceinline__ h2 u2h(unsigned int u) {
  union { unsigned int u; h2 h; } x; x.u = u; return x.h;
}
static __device__ __forceinline__ unsigned int pkbf(float a, float b) {
  return (unsigned int)f2bf(a) | ((unsigned int)f2bf(b) << 16);
}

// ---------------------------------------------------------------------------
// Kernel 1: QKV projection (fp32 in, bf16 out).
// Q,K -> [b][h][s][d] ; V -> [b][v][d][s].
// ---------------------------------------------------------------------------
__global__ __launch_bounds__(256) void ath_qkv(
    const float* __restrict__ inp,
    const float* __restrict__ Wq,
    const float* __restrict__ Wk,
    const float* __restrict__ Wv,
    const float* __restrict__ Aq,
    const float* __restrict__ Ak,
    const float* __restrict__ Av,
    unsigned short* __restrict__ ws)
{
  const int sblk = blockIdx.x;
  const int nblk = blockIdx.y;
  const int z = blockIdx.z;
  const int b = z / 3, p = z % 3;
  const float* W  = (p == 0) ? Wq : ((p == 1) ? Wk : Wv);
  const float* Ap = (p == 0) ? Aq : ((p == 1) ? Ak : Av);
  const float sig = 1.0f / (1.0f + __expf(-Ap[0]));

  __shared__ __align__(16) unsigned short As[64][40];
  __shared__ __align__(16) unsigned short Bs[64][40];

  const int tid = threadIdx.x;
  const int w = tid >> 6, lane = tid & 63;
  const int l15 = lane & 15, quad = lane >> 4;

  floatx4 acc[4];
#pragma unroll
  for (int i = 0; i < 4; ++i) acc[i] = (floatx4){0.f, 0.f, 0.f, 0.f};

  for (int cc = 0; cc < 16; ++cc) {
    const int c0 = cc * 32;
    __syncthreads();
#pragma unroll
    for (int t = 0; t < 2; ++t) {
      const int i = tid * 2 + t;
      const int c = i >> 4, sq = i & 15;
      const floatx4 g = *(const floatx4*)(inp + ((size_t)(b * C_INN + c0 + c) * SEQL + sblk * 64 + sq * 4));
      As[sq * 4 + 0][c] = f2bf(g[0]); As[sq * 4 + 1][c] = f2bf(g[1]);
      As[sq * 4 + 2][c] = f2bf(g[2]); As[sq * 4 + 3][c] = f2bf(g[3]);
    }
#pragma unroll
    for (int t = 0; t < 2; ++t) {
      const int i = tid * 2 + t;
      const int c = i >> 4, nq = i & 15;
      const floatx4 g = *(const floatx4*)(W + ((size_t)(c0 + c) * 1024 + nblk * 64 + nq * 4));
      Bs[nq * 4 + 0][c] = f2bf(g[0]); Bs[nq * 4 + 1][c] = f2bf(g[1]);
      Bs[nq * 4 + 2][c] = f2bf(g[2]); Bs[nq * 4 + 3][c] = f2bf(g[3]);
    }
    __syncthreads();
    const short8 a = *(const short8*)&As[w * 16 + l15][quad * 8];
#pragma unroll
    for (int nt = 0; nt < 4; ++nt) {
      const short8 bb = *(const short8*)&Bs[nt * 16 + l15][quad * 8];
      acc[nt] = __builtin_amdgcn_mfma_f32_16x16x32_bf16(a, bb, acc[nt], 0, 0, 0);
    }
  }

  unsigned short* out = ws + (size_t)p * ((size_t)B_S * N_H * SEQL * D_K);
#pragma unroll
  for (int nt = 0; nt < 4; ++nt) {
    const int h = l15;
    const int d = nblk * 4 + nt;
#pragma unroll
    for (int r = 0; r < 4; ++r) {
      const int s = sblk * 64 + w * 16 + quad * 4 + r;
      const float vout = acc[nt][r] * sig;
      if (p == 2) out[((size_t)((b * N_H + h) * D_K + d)) * SEQL + s] = f2bf(vout);
      else        out[((size_t)((b * N_H + h) * SEQL + s)) * D_K + d] = f2bf(vout);
    }
  }
}

// ---------------------------------------------------------------------------
// K2a: partial l. grid(64 qblk, KSL, 2 b). Wave w owns k-tile w (16 k), all 16
// heads. J^T = mfma(K,Q): rows k=quad*4+r, cols q=l15 -> [k][q]*9 store hits
// 16 banks (4-way). Barrier-free J->EL chain inside the wave.
// ---------------------------------------------------------------------------
__global__ __launch_bounds__(256, 4) void ath_lpart(
    const float* __restrict__ maskp,
    const float* __restrict__ Wl,
    const unsigned short* __restrict__ qkv,
    float* __restrict__ lp)
{
  const int qblk = blockIdx.x;
  const int ks   = blockIdx.y;
  const int b    = blockIdx.z;
  const int tid = threadIdx.x;
  const int w = tid >> 6, lane = tid & 63;
  const int l15 = lane & 15, quad = lane >> 4;

  const unsigned short* Qf = qkv;
  const unsigned short* Kf = qkv + (size_t)B_S * N_H * SEQL * D_K;

  __shared__ unsigned int JtU[4][2304];  // [k16][q16][hp8+pad1] f16 pairs, 36 KB
  __shared__ float Ms[SEQL];             // 4 KB

  {
    const floatx4 mv = *(const floatx4*)(maskp + b * SEQL + tid * 4);
    *(floatx4*)&Ms[tid * 4] = mv;
  }

  // Wl columns (g = quad*4+gg) as f16 pairs over h
  unsigned int WlTp[4][8];
#pragma unroll
  for (int gg = 0; gg < 4; ++gg)
#pragma unroll
    for (int hp = 0; hp < 8; ++hp)
      WlTp[gg][hp] = pkh2(Wl[(2 * hp) * 16 + quad * 4 + gg],
                          Wl[(2 * hp + 1) * 16 + quad * 4 + gg]);

  __syncthreads();  // Ms visible

  const int kabs0 = ks * (SEQL / KSL) + w * 16;

  // ---- J for all 16 heads of this wave's tile (rows k, cols q) ----
#pragma unroll
  for (int hg = 0; hg < 2; ++hg) {
    floatx4 jc[8];
#pragma unroll
    for (int hh = 0; hh < 8; ++hh) {
      const int h = hg * 8 + hh;
      const unsigned short* qb = Qf + ((size_t)((b * N_H + h) * SEQL) + qblk * 16 + l15) * D_K;
      const unsigned short* kb = Kf + ((size_t)((b * N_H + h) * SEQL) + kabs0 + l15) * D_K;
      const short8 q0 = *(const short8*)(qb + quad * 8);
      const short8 q1 = *(const short8*)(qb + 32 + quad * 8);
      const short8 k0 = *(const short8*)(kb + quad * 8);
      const short8 k1 = *(const short8*)(kb + 32 + quad * 8);
      floatx4 c = (floatx4){0.f, 0.f, 0.f, 0.f};
      c = __builtin_amdgcn_mfma_f32_16x16x32_bf16(k0, q0, c, 0, 0, 0);  // A=K: rows k, cols q
      c = __builtin_amdgcn_mfma_f32_16x16x32_bf16(k1, q1, c, 0, 0, 0);
      jc[hh] = c;
    }
    // lane holds J[k=quad*4+r][q=l15] -> [k][q] layout, banks 9*l15 (4-way)
#pragma unroll
    for (int r = 0; r < 4; ++r) {
      const int base = ((quad * 4 + r) * 16 + l15) * 9 + hg * 4;
#pragma unroll
      for (int jj = 0; jj < 4; ++jj)
        JtU[w][base + jj] = pkh2(jc[2 * jj][r], jc[2 * jj + 1][r]);
    }
  }

  // ---- EL mix + exp + l accumulate. Lane role: q=l15, g=quad*4+gg ----
  float l_acc[4] = {0.f, 0.f, 0.f, 0.f};
#pragma unroll 4
  for (int k = 0; k < 16; ++k) {
    const int jb = (k * 16 + l15) * 9;
    unsigned int ju[8];
#pragma unroll
    for (int hp = 0; hp < 8; ++hp) ju[hp] = JtU[w][jb + hp];
    const float m = Ms[kabs0 + k];
    h2 eh[4] = {(h2)(_Float16)0, (h2)(_Float16)0, (h2)(_Float16)0, (h2)(_Float16)0};
#pragma unroll
    for (int hp = 0; hp < 8; ++hp) {
      const h2 jv = u2h(ju[hp]);
      eh[0] += jv * u2h(WlTp[0][hp]);
      eh[1] += jv * u2h(WlTp[1][hp]);
      eh[2] += jv * u2h(WlTp[2][hp]);
      eh[3] += jv * u2h(WlTp[3][hp]);
    }
#pragma unroll
    for (int gg = 0; gg < 4; ++gg) {
      const float e = (float)eh[gg][0] + (float)eh[gg][1] - m;
      l_acc[gg] += __expf(fminf(fmaxf(e, -60.f), 60.f));
    }
  }

  // ---- cross-wave reduce over the 4 k-tiles (reuse JtU slice 0) ----
  __syncthreads();
  float* Ls = (float*)&JtU[0][0];
#pragma unroll
  for (int gg = 0; gg < 4; ++gg)
    Ls[w * 256 + l15 * 16 + quad * 4 + gg] = l_acc[gg];
  __syncthreads();
  {
    const float s = Ls[tid] + Ls[256 + tid] + Ls[512 + tid] + Ls[768 + tid];
    const int q = tid >> 4, g = tid & 15;
    lp[((size_t)((ks * 2 + b) * SEQL + qblk * 16 + q)) * 16 + g] = s;
  }
}

// ---------------------------------------------------------------------------
// K2r: invl = 1 / sum_ks lp. grid(128, 256 thr).
// ---------------------------------------------------------------------------
__global__ __launch_bounds__(256) void ath_linv(
    const float* __restrict__ lp, float* __restrict__ invl)
{
  const int t = blockIdx.x * 256 + threadIdx.x;
  const int b = t >> 14, rem = t & 16383;
  float s = 0.f;
#pragma unroll
  for (int ks = 0; ks < KSL; ++ks) s += lp[(size_t)((ks * 2 + b)) * 16384 + rem];
  invl[t] = 1.0f / fmaxf(s, 1e-37f);
}

// ---------------------------------------------------------------------------
// K2b: partial O. grid(64 qblk, KSO, 2 b). kchunk=128 -> 2 rounds of 64 k.
// Per round: wave w owns k-tile rd*4+w (J->EL->U barrier-free), barrier,
// cross-wave V-phase (mfma 16x16x32 bf16, wave w: v=4w..4w+3), barrier.
// ---------------------------------------------------------------------------
__global__ __launch_bounds__(256, 2) void ath_opart(
    const float* __restrict__ maskp,
    const float* __restrict__ Wl,
    const float* __restrict__ Ww,
    const unsigned short* __restrict__ qkv,
    const float* __restrict__ invl,
    unsigned short* __restrict__ Obp)
{
  const int qblk = blockIdx.x;
  const int ks   = blockIdx.y;
  const int b    = blockIdx.z;
  const int tid = threadIdx.x;
  const int w = tid >> 6, lane = tid & 63;
  const int l15 = lane & 15, quad = lane >> 4;

  const unsigned short* Qf = qkv;
  const unsigned short* Kf = qkv + (size_t)B_S * N_H * SEQL * D_K;
  const unsigned short* Vf = qkv + 2 * (size_t)B_S * N_H * SEQL * D_K;

  __shared__ unsigned int JtU[4][2304];   // per-wave J/P slice, 36 KB
  __shared__ unsigned int UsU[16 * 16 * 34];  // U bf16 [v16][q16][k64 pad->34 uints], 34.8 KB
  __shared__ float Ms[SEQL];              // 4 KB

  {
    const floatx4 mv = *(const floatx4*)(maskp + b * SEQL + tid * 4);
    *(floatx4*)&Ms[tid * 4] = mv;
  }

  unsigned int WlTp[4][8], WwTp[4][8];
#pragma unroll
  for (int gg = 0; gg < 4; ++gg)
#pragma unroll
    for (int hp = 0; hp < 8; ++hp) {
      WlTp[gg][hp] = pkh2(Wl[(2 * hp) * 16 + quad * 4 + gg],
                          Wl[(2 * hp + 1) * 16 + quad * 4 + gg]);
      WwTp[gg][hp] = pkh2(Ww[(2 * hp) * 16 + quad * 4 + gg],
                          Ww[(2 * hp + 1) * 16 + quad * 4 + gg]);
    }

  float inv[4];
#pragma unroll
  for (int gg = 0; gg < 4; ++gg)
    inv[gg] = invl[(size_t)b * 16384 + (qblk * 16 + l15) * 16 + quad * 4 + gg];

  floatx4 oacc[4][4];
#pragma unroll
  for (int a = 0; a < 4; ++a)
#pragma unroll
    for (int d = 0; d < 4; ++d) oacc[a][d] = (floatx4){0.f, 0.f, 0.f, 0.f};

  __syncthreads();  // Ms visible

  const int kchunk = SEQL / KSO;   // 128

  for (int rd = 0; rd < 2; ++rd) {
    const int kabs0 = ks * kchunk + (rd * 4 + w) * 16;

    // ---- J for all 16 heads (wave-private; rows k, cols q) ----
#pragma unroll
    for (int hg = 0; hg < 2; ++hg) {
      floatx4 jc[8];
#pragma unroll
      for (int hh = 0; hh < 8; ++hh) {
        const int h = hg * 8 + hh;
        const unsigned short* qb = Qf + ((size_t)((b * N_H + h) * SEQL) + qblk * 16 + l15) * D_K;
        const unsigned short* kb = Kf + ((size_t)((b * N_H + h) * SEQL) + kabs0 + l15) * D_K;
        const short8 q0 = *(const short8*)(qb + quad * 8);
        const short8 q1 = *(const short8*)(qb + 32 + quad * 8);
        const short8 k0 = *(const short8*)(kb + quad * 8);
        const short8 k1 = *(const short8*)(kb + 32 + quad * 8);
        floatx4 c = (floatx4){0.f, 0.f, 0.f, 0.f};
        c = __builtin_amdgcn_mfma_f32_16x16x32_bf16(k0, q0, c, 0, 0, 0);  // A=K: rows k
        c = __builtin_amdgcn_mfma_f32_16x16x32_bf16(k1, q1, c, 0, 0, 0);
        jc[hh] = c;
      }
#pragma unroll
      for (int r = 0; r < 4; ++r) {
        const int base = ((quad * 4 + r) * 16 + l15) * 9 + hg * 4;  // [k][q], banks 9*l15
#pragma unroll
        for (int jj = 0; jj < 4; ++jj)
          JtU[w][base + jj] = pkh2(jc[2 * jj][r], jc[2 * jj + 1][r]);
      }
    }

    // ---- EL mix -> P f16 pairs, in-place over J (wave-lockstep-safe) ----
#pragma unroll 4
    for (int k = 0; k < 16; ++k) {
      const int jb = (k * 16 + l15) * 9;
      unsigned int ju[8];
#pragma unroll
      for (int hp = 0; hp < 8; ++hp) ju[hp] = JtU[w][jb + hp];
      const float m = Ms[kabs0 + k];
      h2 eh[4] = {(h2)(_Float16)0, (h2)(_Float16)0, (h2)(_Float16)0, (h2)(_Float16)0};
#pragma unroll
      for (int hp = 0; hp < 8; ++hp) {
        const h2 jv = u2h(ju[hp]);
        eh[0] += jv * u2h(WlTp[0][hp]);
        eh[1] += jv * u2h(WlTp[1][hp]);
        eh[2] += jv * u2h(WlTp[2][hp]);
        eh[3] += jv * u2h(WlTp[3][hp]);
      }
      float p[4];
#pragma unroll
      for (int gg = 0; gg < 4; ++gg) {
        const float e = (float)eh[gg][0] + (float)eh[gg][1] - m;
        p[gg] = __expf(fminf(fmaxf(e, -60.f), 60.f)) * inv[gg];
      }
      JtU[w][jb + quad * 2 + 0] = pkh2(p[0], p[1]);
      JtU[w][jb + quad * 2 + 1] = pkh2(p[2], p[3]);
    }

    // ---- U mix: lane role q=l15, v=quad*4+vv -> Us bf16 [v][q][klocal] ----
#pragma unroll 4
    for (int kp = 0; kp < 8; ++kp) {
      float ue[4] = {0.f, 0.f, 0.f, 0.f}, uo[4] = {0.f, 0.f, 0.f, 0.f};
#pragma unroll
      for (int par = 0; par < 2; ++par) {
        const int jb = ((kp * 2 + par) * 16 + l15) * 9;
        unsigned int pu[8];
#pragma unroll
        for (int gp = 0; gp < 8; ++gp) pu[gp] = JtU[w][jb + gp];
        h2 uh[4] = {(h2)(_Float16)0, (h2)(_Float16)0, (h2)(_Float16)0, (h2)(_Float16)0};
#pragma unroll
        for (int gp = 0; gp < 8; ++gp) {
          const h2 pv = u2h(pu[gp]);
          uh[0] += pv * u2h(WwTp[0][gp]);
          uh[1] += pv * u2h(WwTp[1][gp]);
          uh[2] += pv * u2h(WwTp[2][gp]);
          uh[3] += pv * u2h(WwTp[3][gp]);
        }
        float* u = par ? uo : ue;
#pragma unroll
        for (int vv = 0; vv < 4; ++vv) u[vv] = (float)uh[vv][0] + (float)uh[vv][1];
      }
#pragma unroll
      for (int vv = 0; vv < 4; ++vv)
        UsU[((quad * 4 + vv) * 16 + l15) * 34 + w * 8 + kp] = pkbf(ue[vv], uo[vv]);
    }

    __syncthreads();  // all waves' Us slices ready

    // ---- V-phase: wave w -> v = 4w..4w+3; K=32 bf16 MFMA over 2 k-pairs ----
    const unsigned short* UsS = (const unsigned short*)UsU;
#pragma unroll
    for (int tp = 0; tp < 2; ++tp) {
      const int kt_abs = ks * kchunk + rd * 64 + tp * 32;
#pragma unroll
      for (int vv = 0; vv < 4; ++vv) {
        const int v = w * 4 + vv;
        const short8 ufr = *(const short8*)&UsS[((v * 16 + l15) * 34) * 2 + tp * 32 + quad * 8];
#pragma unroll
        for (int dt = 0; dt < 4; ++dt) {
          const short8 vfr = *(const short8*)(Vf +
              ((size_t)((b * N_H + v) * D_K + dt * 16 + l15)) * SEQL + kt_abs + quad * 8);
          oacc[vv][dt] = __builtin_amdgcn_mfma_f32_16x16x32_bf16(ufr, vfr, oacc[vv][dt], 0, 0, 0);
        }
      }
    }

    __syncthreads();  // Us free for next round
  }

  // write partial O bf16: Obp[ks][b][q][d*16+v]
#pragma unroll
  for (int vv = 0; vv < 4; ++vv) {
    const int v = w * 4 + vv;
#pragma unroll
    for (int dt = 0; dt < 4; ++dt) {
      const int d = dt * 16 + l15;
#pragma unroll
      for (int r = 0; r < 4; ++r) {
        const int q = qblk * 16 + quad * 4 + r;
        Obp[(size_t)ks * BQJ + ((size_t)(b * SEQL + q)) * 1024 + d * 16 + v] = f2bf(oacc[vv][dt][r]);
      }
    }
  }
}

// ---------------------------------------------------------------------------
// K2s: Obsum = sum_ks Obp. grid(1024, 256 thr).
// ---------------------------------------------------------------------------
__global__ __launch_bounds__(256) void ath_osum(
    const unsigned short* __restrict__ Obp,
    unsigned short* __restrict__ Obsum)
{
  const size_t i = ((size_t)blockIdx.x * 256 + threadIdx.x) * 8;
  float a[8];
#pragma unroll
  for (int e = 0; e < 8; ++e) a[e] = 0.f;
#pragma unroll
  for (int ks = 0; ks < KSO; ++ks) {
    const short8 v = *(const short8*)(Obp + (size_t)ks * BQJ + i);
#pragma unroll
    for (int e = 0; e < 8; ++e) a[e] += bf2f((unsigned short)v[e]);
  }
  short8 o;
#pragma unroll
  for (int e = 0; e < 8; ++e) o[e] = (short)f2bf(a[e]);
  *(short8*)(Obsum + i) = o;
}

// ---------------------------------------------------------------------------
// Kernel 3: out[b][co][q] = inp + sum_j Obsum[b][q][j] * Wo[j][co]. fp32 out.
// ---------------------------------------------------------------------------
__global__ __launch_bounds__(256) void ath_out(
    const float* __restrict__ inp,
    const float* __restrict__ Wo,
    const unsigned short* __restrict__ Ob,
    float* __restrict__ out)
{
  const int qblk = blockIdx.x;
  const int cblk = blockIdx.y;
  const int b    = blockIdx.z;
  const int tid = threadIdx.x;
  const int w = tid >> 6, lane = tid & 63;
  const int l15 = lane & 15, quad = lane >> 4;

  __shared__ __align__(16) unsigned short Os[64][40];
  __shared__ __align__(16) unsigned short Wt[64][40];

  floatx4 acc[4];
#pragma unroll
  for (int i = 0; i < 4; ++i) acc[i] = (floatx4){0.f, 0.f, 0.f, 0.f};

  for (int jc = 0; jc < 32; ++jc) {
    const int j0 = jc * 32;
    __syncthreads();
    {
      const int q = tid >> 2, jq = tid & 3;
      const unsigned short* g = Ob + ((size_t)(b * SEQL + qblk * 64 + q)) * 1024 + j0 + jq * 8;
      *(short8*)&Os[q][jq * 8] = *(const short8*)g;
    }
#pragma unroll
    for (int t = 0; t < 2; ++t) {
      const int i = tid * 2 + t;
      const int j = i >> 4, cq = i & 15;
      const floatx4 g = *(const floatx4*)(Wo + ((size_t)(j0 + j) * 512 + cblk * 64 + cq * 4));
      Wt[cq * 4 + 0][j] = f2bf(g[0]); Wt[cq * 4 + 1][j] = f2bf(g[1]);
      Wt[cq * 4 + 2][j] = f2bf(g[2]); Wt[cq * 4 + 3][j] = f2bf(g[3]);
    }
    __syncthreads();
    const short8 a = *(const short8*)&Os[w * 16 + l15][quad * 8];
#pragma unroll
    for (int nt = 0; nt < 4; ++nt) {
      const short8 bb = *(const short8*)&Wt[nt * 16 + l15][quad * 8];
      acc[nt] = __builtin_amdgcn_mfma_f32_16x16x32_bf16(a, bb, acc[nt], 0, 0, 0);
    }
  }

#pragma unroll
  for (int nt = 0; nt < 4; ++nt) {
    const int co = cblk * 64 + nt * 16 + l15;
    const int qb = qblk * 64 + w * 16 + quad * 4;
    const float* ip = inp + ((size_t)(b * 512 + co)) * SEQL + qb;
    float* op = out + ((size_t)(b * 512 + co)) * SEQL + qb;
#pragma unroll
    for (int r = 0; r < 4; ++r) op[r] = acc[nt][r] + ip[r];
  }
}

// ---------------------------------------------------------------------------
extern "C" void kernel_launch(void* const* d_in, const int* in_sizes, int n_in,
                              void* d_out, int out_size, void* d_ws, size_t ws_size,
                              hipStream_t stream) {
  (void)in_sizes; (void)n_in; (void)out_size; (void)ws_size;
  const float* inp   = (const float*)d_in[0];
  const float* maskp = (const float*)d_in[1];
  const float* Wq    = (const float*)d_in[2];
  const float* Wk    = (const float*)d_in[3];
  const float* Wv    = (const float*)d_in[4];
  const float* Aq    = (const float*)d_in[5];
  const float* Ak    = (const float*)d_in[6];
  const float* Av    = (const float*)d_in[7];
  const float* Wl    = (const float*)d_in[8];
  const float* Ww    = (const float*)d_in[9];
  const float* Wo    = (const float*)d_in[10];

  const size_t MB = 1u << 20;
  unsigned short* qkv   = (unsigned short*)d_ws;                       // 12 MB bf16 Q,K,V
  unsigned short* Obsum = (unsigned short*)((char*)d_ws + 12 * MB);    // 4 MB bf16
  float*          invl  = (float*)((char*)d_ws + 16 * MB);             // 128 KB
  float*          lp    = (float*)((char*)d_ws + 18 * MB);             // 2 MB (dead before Obp use)
  unsigned short* Obp   = (unsigned short*)((char*)d_ws + 18 * MB);    // KSO*4 MB = 32 MB
  float* out = (float*)d_out;

  ath_qkv<<<dim3(16, 16, 6), 256, 0, stream>>>(inp, Wq, Wk, Wv, Aq, Ak, Av, qkv);
  ath_lpart<<<dim3(64, KSL, 2), 256, 0, stream>>>(maskp, Wl, qkv, lp);
  ath_linv<<<dim3(128), 256, 0, stream>>>(lp, invl);
  ath_opart<<<dim3(64, KSO, 2), 256, 0, stream>>>(maskp, Wl, Ww, qkv, invl, Obp);
  ath_osum<<<dim3(1024), 256, 0, stream>>>(Obp, Obsum);
  ath_out<<<dim3(16, 8, 2), 256, 0, stream>>>(inp, Wo, Obsum, out);
}

// Round 11
// 318.930 us; speedup vs baseline: 1.6089x; 1.1484x over previous
//
#include <hip/hip_runtime.h>
#include <hip/hip_bf16.h>

// TalkingHeads: BS=2, C_IN=512, SEQ=1024, DK=DV=64, H=16. fp32 I/O.
// Round 11: keep r10 attention core (measured 121us opart); attack the other
// ~245us: pre-transpose inp/W/Wo to bf16 once (ath_tr), making qkv/ath_out
// staging single-b128 row copies (round-0 staging was 8-way-conflicted scalar
// transpose stores). Drop Ms LDS from lpart/opart (broadcast global mask).

#define B_S  2
#define C_INN 512
#define SEQL 1024
#define D_K  64
#define N_H  16
#define BQJ  (2 * 1024 * 1024)   // elements of one O partial [b][q][j]
#define KSL  16                  // lpart split
#define KSO  8                   // opart split

typedef __attribute__((ext_vector_type(4))) float floatx4;
typedef __attribute__((ext_vector_type(8))) short short8;
typedef __attribute__((ext_vector_type(2))) unsigned int uint2v;
typedef __fp16 h2raw __attribute__((ext_vector_type(2)));
typedef _Float16 h2 __attribute__((ext_vector_type(2)));

static __device__ __forceinline__ float bf2f(unsigned short u) {
  union { unsigned int i; float f; } x; x.i = ((unsigned int)u) << 16; return x.f;
}
static __device__ __forceinline__ unsigned short f2bf(float f) {
  union { float f; unsigned int i; } x; x.f = f;
  return (unsigned short)((x.i + 0x7fffu + ((x.i >> 16) & 1u)) >> 16);
}
static __device__ __forceinline__ unsigned int pkh2(float a, float b) {
  h2raw r = __builtin_amdgcn_cvt_pkrtz(a, b);
  union { h2raw h; unsigned int u; } x; x.h = r; return x.u;
}
static __device__ __forceinline__ h2 u2h(unsigned int u) {
  union { unsigned int u; h2 h; } x; x.u = u; return x.h;
}
static __device__ __forceinline__ unsigned int pkbf(float a, float b) {
  return (unsigned int)f2bf(a) | ((unsigned int)f2bf(b) << 16);
}

// ---------------------------------------------------------------------------
// K0: batched transpose+convert. z: 0,1=inp b0/b1 (512x1024 -> [s][c]);
// 2,3,4=Wq/Wk/Wv (512x1024 -> [n][c]); 5=Wo (1024x512 -> [co][j]). bf16 out.
// ---------------------------------------------------------------------------
__global__ __launch_bounds__(256) void ath_tr(
    const float* __restrict__ inp, const float* __restrict__ Wq,
    const float* __restrict__ Wk,  const float* __restrict__ Wv,
    const float* __restrict__ Wo,
    unsigned short* __restrict__ inpT, unsigned short* __restrict__ WT,
    unsigned short* __restrict__ WoT)
{
  const int z = blockIdx.z;
  const float* src; unsigned short* dst; int R, C;
  if      (z == 0) { src = inp;              dst = inpT;                R = 512;  C = 1024; }
  else if (z == 1) { src = inp + 512 * 1024; dst = inpT + 1024 * 512;   R = 512;  C = 1024; }
  else if (z == 2) { src = Wq;               dst = WT;                  R = 512;  C = 1024; }
  else if (z == 3) { src = Wk;               dst = WT + 1024 * 512;     R = 512;  C = 1024; }
  else if (z == 4) { src = Wv;               dst = WT + 2 * 1024 * 512; R = 512;  C = 1024; }
  else             { src = Wo;               dst = WoT;                 R = 1024; C = 512;  }
  const int ct = blockIdx.x, rt = blockIdx.y;
  if (ct * 32 >= C || rt * 32 >= R) return;

  __shared__ float Ts[32][33];
  const int t = threadIdx.x;
  {
    const int r = t >> 3, c4 = (t & 7) * 4;
    const floatx4 g = *(const floatx4*)(src + (size_t)(rt * 32 + r) * C + ct * 32 + c4);
    Ts[r][c4 + 0] = g[0]; Ts[r][c4 + 1] = g[1];
    Ts[r][c4 + 2] = g[2]; Ts[r][c4 + 3] = g[3];
  }
  __syncthreads();
  {
    const int i = t >> 3, k4 = (t & 7) * 4;  // out row i (C dim), cols k4 (R dim)
    const unsigned int o0 = pkbf(Ts[k4 + 0][i], Ts[k4 + 1][i]);
    const unsigned int o1 = pkbf(Ts[k4 + 2][i], Ts[k4 + 3][i]);
    *(uint2v*)(dst + (size_t)(ct * 32 + i) * R + rt * 32 + k4) = (uint2v){o0, o1};
  }
}

// ---------------------------------------------------------------------------
// K1: QKV projection from pre-transposed bf16 inputs.
// Q,K -> [b][h][s][d] ; V -> [b][v][d][s]. Staging = b128 row copies.
// ---------------------------------------------------------------------------
__global__ __launch_bounds__(256) void ath_qkv(
    const unsigned short* __restrict__ inpT,  // [b][s][c]
    const unsigned short* __restrict__ WT,    // [p][n][c]
    const float* __restrict__ Aq,
    const float* __restrict__ Ak,
    const float* __restrict__ Av,
    unsigned short* __restrict__ ws)
{
  const int sblk = blockIdx.x;
  const int nblk = blockIdx.y;
  const int z = blockIdx.z;
  const int b = z / 3, p = z % 3;
  const float* Ap = (p == 0) ? Aq : ((p == 1) ? Ak : Av);
  const float sig = 1.0f / (1.0f + __expf(-Ap[0]));

  __shared__ __align__(16) unsigned short As[64][40];
  __shared__ __align__(16) unsigned short Bs[64][40];

  const int tid = threadIdx.x;
  const int w = tid >> 6, lane = tid & 63;
  const int l15 = lane & 15, quad = lane >> 4;
  const int srow = tid >> 2, sc8 = (tid & 3) * 8;

  floatx4 acc[4];
#pragma unroll
  for (int i = 0; i < 4; ++i) acc[i] = (floatx4){0.f, 0.f, 0.f, 0.f};

  for (int cc = 0; cc < 16; ++cc) {
    const int c0 = cc * 32;
    __syncthreads();
    *(short8*)&As[srow][sc8] =
        *(const short8*)(inpT + ((size_t)(b * 1024 + sblk * 64 + srow)) * 512 + c0 + sc8);
    *(short8*)&Bs[srow][sc8] =
        *(const short8*)(WT + ((size_t)(p * 1024 + nblk * 64 + srow)) * 512 + c0 + sc8);
    __syncthreads();
    const short8 a = *(const short8*)&As[w * 16 + l15][quad * 8];
#pragma unroll
    for (int nt = 0; nt < 4; ++nt) {
      const short8 bb = *(const short8*)&Bs[nt * 16 + l15][quad * 8];
      acc[nt] = __builtin_amdgcn_mfma_f32_16x16x32_bf16(a, bb, acc[nt], 0, 0, 0);
    }
  }

  unsigned short* out = ws + (size_t)p * ((size_t)B_S * N_H * SEQL * D_K);
#pragma unroll
  for (int nt = 0; nt < 4; ++nt) {
    const int h = l15;
    const int d = nblk * 4 + nt;
#pragma unroll
    for (int r = 0; r < 4; ++r) {
      const int s = sblk * 64 + w * 16 + quad * 4 + r;
      const float vout = acc[nt][r] * sig;
      if (p == 2) out[((size_t)((b * N_H + h) * D_K + d)) * SEQL + s] = f2bf(vout);
      else        out[((size_t)((b * N_H + h) * SEQL + s)) * D_K + d] = f2bf(vout);
    }
  }
}

// ---------------------------------------------------------------------------
// K2a: partial l. grid(64 qblk, KSL, 2 b). Wave w owns k-tile w (16 k), all 16
// heads. J^T = mfma(K,Q). Mask via broadcast global loads (no Ms LDS).
// ---------------------------------------------------------------------------
__global__ __launch_bounds__(256, 4) void ath_lpart(
    const float* __restrict__ maskp,
    const float* __restrict__ Wl,
    const unsigned short* __restrict__ qkv,
    float* __restrict__ lp)
{
  const int qblk = blockIdx.x;
  const int ks   = blockIdx.y;
  const int b    = blockIdx.z;
  const int tid = threadIdx.x;
  const int w = tid >> 6, lane = tid & 63;
  const int l15 = lane & 15, quad = lane >> 4;

  const unsigned short* Qf = qkv;
  const unsigned short* Kf = qkv + (size_t)B_S * N_H * SEQL * D_K;

  __shared__ unsigned int JtU[4][2304];  // [k16][q16][hp8+pad1] f16 pairs, 36 KB

  unsigned int WlTp[4][8];
#pragma unroll
  for (int gg = 0; gg < 4; ++gg)
#pragma unroll
    for (int hp = 0; hp < 8; ++hp)
      WlTp[gg][hp] = pkh2(Wl[(2 * hp) * 16 + quad * 4 + gg],
                          Wl[(2 * hp + 1) * 16 + quad * 4 + gg]);

  const int kabs0 = ks * (SEQL / KSL) + w * 16;

#pragma unroll
  for (int hg = 0; hg < 2; ++hg) {
    floatx4 jc[8];
#pragma unroll
    for (int hh = 0; hh < 8; ++hh) {
      const int h = hg * 8 + hh;
      const unsigned short* qb = Qf + ((size_t)((b * N_H + h) * SEQL) + qblk * 16 + l15) * D_K;
      const unsigned short* kb = Kf + ((size_t)((b * N_H + h) * SEQL) + kabs0 + l15) * D_K;
      const short8 q0 = *(const short8*)(qb + quad * 8);
      const short8 q1 = *(const short8*)(qb + 32 + quad * 8);
      const short8 k0 = *(const short8*)(kb + quad * 8);
      const short8 k1 = *(const short8*)(kb + 32 + quad * 8);
      floatx4 c = (floatx4){0.f, 0.f, 0.f, 0.f};
      c = __builtin_amdgcn_mfma_f32_16x16x32_bf16(k0, q0, c, 0, 0, 0);  // A=K: rows k
      c = __builtin_amdgcn_mfma_f32_16x16x32_bf16(k1, q1, c, 0, 0, 0);
      jc[hh] = c;
    }
#pragma unroll
    for (int r = 0; r < 4; ++r) {
      const int base = ((quad * 4 + r) * 16 + l15) * 9 + hg * 4;
#pragma unroll
      for (int jj = 0; jj < 4; ++jj)
        JtU[w][base + jj] = pkh2(jc[2 * jj][r], jc[2 * jj + 1][r]);
    }
  }

  float l_acc[4] = {0.f, 0.f, 0.f, 0.f};
#pragma unroll 4
  for (int k = 0; k < 16; ++k) {
    const int jb = (k * 16 + l15) * 9;
    unsigned int ju[8];
#pragma unroll
    for (int hp = 0; hp < 8; ++hp) ju[hp] = JtU[w][jb + hp];
    const float m = maskp[b * SEQL + kabs0 + k];  // broadcast load
    h2 eh[4] = {(h2)(_Float16)0, (h2)(_Float16)0, (h2)(_Float16)0, (h2)(_Float16)0};
#pragma unroll
    for (int hp = 0; hp < 8; ++hp) {
      const h2 jv = u2h(ju[hp]);
      eh[0] += jv * u2h(WlTp[0][hp]);
      eh[1] += jv * u2h(WlTp[1][hp]);
      eh[2] += jv * u2h(WlTp[2][hp]);
      eh[3] += jv * u2h(WlTp[3][hp]);
    }
#pragma unroll
    for (int gg = 0; gg < 4; ++gg) {
      const float e = (float)eh[gg][0] + (float)eh[gg][1] - m;
      l_acc[gg] += __expf(fminf(fmaxf(e, -60.f), 60.f));
    }
  }

  __syncthreads();
  float* Ls = (float*)&JtU[0][0];
#pragma unroll
  for (int gg = 0; gg < 4; ++gg)
    Ls[w * 256 + l15 * 16 + quad * 4 + gg] = l_acc[gg];
  __syncthreads();
  {
    const float s = Ls[tid] + Ls[256 + tid] + Ls[512 + tid] + Ls[768 + tid];
    const int q = tid >> 4, g = tid & 15;
    lp[((size_t)((ks * 2 + b) * SEQL + qblk * 16 + q)) * 16 + g] = s;
  }
}

// ---------------------------------------------------------------------------
// K2r: invl = 1 / sum_ks lp. grid(128, 256 thr).
// ---------------------------------------------------------------------------
__global__ __launch_bounds__(256) void ath_linv(
    const float* __restrict__ lp, float* __restrict__ invl)
{
  const int t = blockIdx.x * 256 + threadIdx.x;
  const int b = t >> 14, rem = t & 16383;
  float s = 0.f;
#pragma unroll
  for (int ks = 0; ks < KSL; ++ks) s += lp[(size_t)((ks * 2 + b)) * 16384 + rem];
  invl[t] = 1.0f / fmaxf(s, 1e-37f);
}

// ---------------------------------------------------------------------------
// K2b: partial O. grid(64 qblk, KSO, 2 b). r10 core, Ms removed.
// ---------------------------------------------------------------------------
__global__ __launch_bounds__(256, 2) void ath_opart(
    const float* __restrict__ maskp,
    const float* __restrict__ Wl,
    const float* __restrict__ Ww,
    const unsigned short* __restrict__ qkv,
    const float* __restrict__ invl,
    unsigned short* __restrict__ Obp)
{
  const int qblk = blockIdx.x;
  const int ks   = blockIdx.y;
  const int b    = blockIdx.z;
  const int tid = threadIdx.x;
  const int w = tid >> 6, lane = tid & 63;
  const int l15 = lane & 15, quad = lane >> 4;

  const unsigned short* Qf = qkv;
  const unsigned short* Kf = qkv + (size_t)B_S * N_H * SEQL * D_K;
  const unsigned short* Vf = qkv + 2 * (size_t)B_S * N_H * SEQL * D_K;

  __shared__ unsigned int JtU[4][2304];       // per-wave J/P slice, 36 KB
  __shared__ unsigned int UsU[16 * 16 * 34];  // U bf16 [v16][q16][k64->34 uints], 34.8 KB
  __shared__ float invls[16][16];

  invls[tid >> 4][tid & 15] =
      invl[(size_t)b * 16384 + (qblk * 16 + (tid >> 4)) * 16 + (tid & 15)];

  unsigned int WlTp[4][8], WwTp[4][8];
#pragma unroll
  for (int gg = 0; gg < 4; ++gg)
#pragma unroll
    for (int hp = 0; hp < 8; ++hp) {
      WlTp[gg][hp] = pkh2(Wl[(2 * hp) * 16 + quad * 4 + gg],
                          Wl[(2 * hp + 1) * 16 + quad * 4 + gg]);
      WwTp[gg][hp] = pkh2(Ww[(2 * hp) * 16 + quad * 4 + gg],
                          Ww[(2 * hp + 1) * 16 + quad * 4 + gg]);
    }

  float inv[4];
#pragma unroll
  for (int gg = 0; gg < 4; ++gg)
    inv[gg] = invl[(size_t)b * 16384 + (qblk * 16 + l15) * 16 + quad * 4 + gg];

  floatx4 oacc[4][4];
#pragma unroll
  for (int a = 0; a < 4; ++a)
#pragma unroll
    for (int d = 0; d < 4; ++d) oacc[a][d] = (floatx4){0.f, 0.f, 0.f, 0.f};

  __syncthreads();  // invls visible

  const int kchunk = SEQL / KSO;   // 128

  for (int rd = 0; rd < 2; ++rd) {
    const int kabs0 = ks * kchunk + (rd * 4 + w) * 16;

    // ---- J for all 16 heads (wave-private; rows k, cols q) ----
#pragma unroll
    for (int hg = 0; hg < 2; ++hg) {
      floatx4 jc[8];
#pragma unroll
      for (int hh = 0; hh < 8; ++hh) {
        const int h = hg * 8 + hh;
        const unsigned short* qb = Qf + ((size_t)((b * N_H + h) * SEQL) + qblk * 16 + l15) * D_K;
        const unsigned short* kb = Kf + ((size_t)((b * N_H + h) * SEQL) + kabs0 + l15) * D_K;
        const short8 q0 = *(const short8*)(qb + quad * 8);
        const short8 q1 = *(const short8*)(qb + 32 + quad * 8);
        const short8 k0 = *(const short8*)(kb + quad * 8);
        const short8 k1 = *(const short8*)(kb + 32 + quad * 8);
        floatx4 c = (floatx4){0.f, 0.f, 0.f, 0.f};
        c = __builtin_amdgcn_mfma_f32_16x16x32_bf16(k0, q0, c, 0, 0, 0);
        c = __builtin_amdgcn_mfma_f32_16x16x32_bf16(k1, q1, c, 0, 0, 0);
        jc[hh] = c;
      }
#pragma unroll
      for (int r = 0; r < 4; ++r) {
        const int base = ((quad * 4 + r) * 16 + l15) * 9 + hg * 4;
#pragma unroll
        for (int jj = 0; jj < 4; ++jj)
          JtU[w][base + jj] = pkh2(jc[2 * jj][r], jc[2 * jj + 1][r]);
      }
    }

    // ---- EL mix -> P f16 pairs, in-place over J (wave-lockstep-safe) ----
#pragma unroll 4
    for (int k = 0; k < 16; ++k) {
      const int jb = (k * 16 + l15) * 9;
      unsigned int ju[8];
#pragma unroll
      for (int hp = 0; hp < 8; ++hp) ju[hp] = JtU[w][jb + hp];
      const float m = maskp[b * SEQL + kabs0 + k];  // broadcast load
      h2 eh[4] = {(h2)(_Float16)0, (h2)(_Float16)0, (h2)(_Float16)0, (h2)(_Float16)0};
#pragma unroll
      for (int hp = 0; hp < 8; ++hp) {
        const h2 jv = u2h(ju[hp]);
        eh[0] += jv * u2h(WlTp[0][hp]);
        eh[1] += jv * u2h(WlTp[1][hp]);
        eh[2] += jv * u2h(WlTp[2][hp]);
        eh[3] += jv * u2h(WlTp[3][hp]);
      }
      float p[4];
#pragma unroll
      for (int gg = 0; gg < 4; ++gg) {
        const float e = (float)eh[gg][0] + (float)eh[gg][1] - m;
        p[gg] = __expf(fminf(fmaxf(e, -60.f), 60.f)) * inv[gg];
      }
      JtU[w][jb + quad * 2 + 0] = pkh2(p[0], p[1]);
      JtU[w][jb + quad * 2 + 1] = pkh2(p[2], p[3]);
    }

    // ---- U mix: lane role q=l15, v=quad*4+vv -> Us bf16 [v][q][klocal] ----
#pragma unroll 4
    for (int kp = 0; kp < 8; ++kp) {
      float ue[4] = {0.f, 0.f, 0.f, 0.f}, uo[4] = {0.f, 0.f, 0.f, 0.f};
#pragma unroll
      for (int par = 0; par < 2; ++par) {
        const int jb = ((kp * 2 + par) * 16 + l15) * 9;
        unsigned int pu[8];
#pragma unroll
        for (int gp = 0; gp < 8; ++gp) pu[gp] = JtU[w][jb + gp];
        h2 uh[4] = {(h2)(_Float16)0, (h2)(_Float16)0, (h2)(_Float16)0, (h2)(_Float16)0};
#pragma unroll
        for (int gp = 0; gp < 8; ++gp) {
          const h2 pv = u2h(pu[gp]);
          uh[0] += pv * u2h(WwTp[0][gp]);
          uh[1] += pv * u2h(WwTp[1][gp]);
          uh[2] += pv * u2h(WwTp[2][gp]);
          uh[3] += pv * u2h(WwTp[3][gp]);
        }
        float* u = par ? uo : ue;
#pragma unroll
        for (int vv = 0; vv < 4; ++vv) u[vv] = (float)uh[vv][0] + (float)uh[vv][1];
      }
#pragma unroll
      for (int vv = 0; vv < 4; ++vv)
        UsU[((quad * 4 + vv) * 16 + l15) * 34 + w * 8 + kp] = pkbf(ue[vv], uo[vv]);
    }

    __syncthreads();  // all waves' Us slices ready

    // ---- V-phase: wave w -> v = 4w..4w+3; K=32 bf16 MFMA over 2 k-pairs ----
    const unsigned short* UsS = (const unsigned short*)UsU;
#pragma unroll
    for (int tp = 0; tp < 2; ++tp) {
      const int kt_abs = ks * kchunk + rd * 64 + tp * 32;
#pragma unroll
      for (int vv = 0; vv < 4; ++vv) {
        const int v = w * 4 + vv;
        const short8 ufr = *(const short8*)&UsS[((v * 16 + l15) * 34) * 2 + tp * 32 + quad * 8];
#pragma unroll
        for (int dt = 0; dt < 4; ++dt) {
          const short8 vfr = *(const short8*)(Vf +
              ((size_t)((b * N_H + v) * D_K + dt * 16 + l15)) * SEQL + kt_abs + quad * 8);
          oacc[vv][dt] = __builtin_amdgcn_mfma_f32_16x16x32_bf16(ufr, vfr, oacc[vv][dt], 0, 0, 0);
        }
      }
    }

    __syncthreads();  // Us free for next round
  }

#pragma unroll
  for (int vv = 0; vv < 4; ++vv) {
    const int v = w * 4 + vv;
#pragma unroll
    for (int dt = 0; dt < 4; ++dt) {
      const int d = dt * 16 + l15;
#pragma unroll
      for (int r = 0; r < 4; ++r) {
        const int q = qblk * 16 + quad * 4 + r;
        Obp[(size_t)ks * BQJ + ((size_t)(b * SEQL + q)) * 1024 + d * 16 + v] = f2bf(oacc[vv][dt][r]);
      }
    }
  }
}

// ---------------------------------------------------------------------------
// K2s: Obsum = sum_ks Obp. grid(1024, 256 thr).
// ---------------------------------------------------------------------------
__global__ __launch_bounds__(256) void ath_osum(
    const unsigned short* __restrict__ Obp,
    unsigned short* __restrict__ Obsum)
{
  const size_t i = ((size_t)blockIdx.x * 256 + threadIdx.x) * 8;
  float a[8];
#pragma unroll
  for (int e = 0; e < 8; ++e) a[e] = 0.f;
#pragma unroll
  for (int ks = 0; ks < KSO; ++ks) {
    const short8 v = *(const short8*)(Obp + (size_t)ks * BQJ + i);
#pragma unroll
    for (int e = 0; e < 8; ++e) a[e] += bf2f((unsigned short)v[e]);
  }
  short8 o;
#pragma unroll
  for (int e = 0; e < 8; ++e) o[e] = (short)f2bf(a[e]);
  *(short8*)(Obsum + i) = o;
}

// ---------------------------------------------------------------------------
// K3: out[b][co][q] = inp + sum_j Obsum[b][q][j] * WoT[co][j]. fp32 out.
// ---------------------------------------------------------------------------
__global__ __launch_bounds__(256) void ath_out(
    const float* __restrict__ inp,
    const unsigned short* __restrict__ WoT,   // [co][j] bf16
    const unsigned short* __restrict__ Ob,
    float* __restrict__ out)
{
  const int qblk = blockIdx.x;
  const int cblk = blockIdx.y;
  const int b    = blockIdx.z;
  const int tid = threadIdx.x;
  const int w = tid >> 6, lane = tid & 63;
  const int l15 = lane & 15, quad = lane >> 4;

  __shared__ __align__(16) unsigned short Os[64][40];
  __shared__ __align__(16) unsigned short Wt[64][40];

  floatx4 acc[4];
#pragma unroll
  for (int i = 0; i < 4; ++i) acc[i] = (floatx4){0.f, 0.f, 0.f, 0.f};

  const int srow = tid >> 2, sj8 = (tid & 3) * 8;

  for (int jc = 0; jc < 32; ++jc) {
    const int j0 = jc * 32;
    __syncthreads();
    *(short8*)&Os[srow][sj8] =
        *(const short8*)(Ob + ((size_t)(b * SEQL + qblk * 64 + srow)) * 1024 + j0 + sj8);
    *(short8*)&Wt[srow][sj8] =
        *(const short8*)(WoT + ((size_t)(cblk * 64 + srow)) * 1024 + j0 + sj8);
    __syncthreads();
    const short8 a = *(const short8*)&Os[w * 16 + l15][quad * 8];
#pragma unroll
    for (int nt = 0; nt < 4; ++nt) {
      const short8 bb = *(const short8*)&Wt[nt * 16 + l15][quad * 8];
      acc[nt] = __builtin_amdgcn_mfma_f32_16x16x32_bf16(a, bb, acc[nt], 0, 0, 0);
    }
  }

#pragma unroll
  for (int nt = 0; nt < 4; ++nt) {
    const int co = cblk * 64 + nt * 16 + l15;
    const int qb = qblk * 64 + w * 16 + quad * 4;
    const float* ip = inp + ((size_t)(b * 512 + co)) * SEQL + qb;
    float* op = out + ((size_t)(b * 512 + co)) * SEQL + qb;
#pragma unroll
    for (int r = 0; r < 4; ++r) op[r] = acc[nt][r] + ip[r];
  }
}

// ---------------------------------------------------------------------------
extern "C" void kernel_launch(void* const* d_in, const int* in_sizes, int n_in,
                              void* d_out, int out_size, void* d_ws, size_t ws_size,
                              hipStream_t stream) {
  (void)in_sizes; (void)n_in; (void)out_size; (void)ws_size;
  const float* inp   = (const float*)d_in[0];
  const float* maskp = (const float*)d_in[1];
  const float* Wq    = (const float*)d_in[2];
  const float* Wk    = (const float*)d_in[3];
  const float* Wv    = (const float*)d_in[4];
  const float* Aq    = (const float*)d_in[5];
  const float* Ak    = (const float*)d_in[6];
  const float* Av    = (const float*)d_in[7];
  const float* Wl    = (const float*)d_in[8];
  const float* Ww    = (const float*)d_in[9];
  const float* Wo    = (const float*)d_in[10];

  const size_t MB = 1u << 20;
  // ws layout (<=50MB). Lifetimes: WT/inpT die after qkv; lp dies after linv;
  // all three are overlapped by Obp (written by opart, later in the stream).
  unsigned short* qkv   = (unsigned short*)d_ws;                       // [0,12) Q,K,V bf16
  unsigned short* Obsum = (unsigned short*)((char*)d_ws + 12 * MB);    // [12,16)
  float*          invl  = (float*)((char*)d_ws + 16 * MB);             // 128 KB
  unsigned short* WoT   = (unsigned short*)((char*)d_ws + 17 * MB);    // [17,18) survives to ath_out
  float*          lp    = (float*)((char*)d_ws + 18 * MB);             // [18,20)
  unsigned short* WT    = (unsigned short*)((char*)d_ws + 20 * MB);    // [20,23)
  unsigned short* inpT  = (unsigned short*)((char*)d_ws + 23 * MB);    // [23,25)
  unsigned short* Obp   = (unsigned short*)((char*)d_ws + 18 * MB);    // [18,50)
  float* out = (float*)d_out;

  ath_tr<<<dim3(32, 32, 6), 256, 0, stream>>>(inp, Wq, Wk, Wv, Wo, inpT, WT, WoT);
  ath_qkv<<<dim3(16, 16, 6), 256, 0, stream>>>(inpT, WT, Aq, Ak, Av, qkv);
  ath_lpart<<<dim3(64, KSL, 2), 256, 0, stream>>>(maskp, Wl, qkv, lp);
  ath_linv<<<dim3(128), 256, 0, stream>>>(lp, invl);
  ath_opart<<<dim3(64, KSO, 2), 256, 0, stream>>>(maskp, Wl, Ww, qkv, invl, Obp);
  ath_osum<<<dim3(1024), 256, 0, stream>>>(Obp, Obsum);
  ath_out<<<dim3(16, 8, 2), 256, 0, stream>>>(inp, WoT, Obsum, out);
}

// Round 12
// 314.449 us; speedup vs baseline: 1.6319x; 1.0143x over previous
//
#include <hip/hip_runtime.h>
#include <hip/hip_bf16.h>

// TalkingHeads: BS=2, C_IN=512, SEQ=1024, DK=DV=64, H=16. fp32 I/O.
// Round 12: r11 pipeline (pre-transposed bf16 operands, b128 staging in
// qkv/out) + reverted mask handling: chunk-sized LDS mask stage (r11's
// per-k global broadcast loads cost +20us in opart; measured).

#define B_S  2
#define C_INN 512
#define SEQL 1024
#define D_K  64
#define N_H  16
#define BQJ  (2 * 1024 * 1024)   // elements of one O partial [b][q][j]
#define KSL  16                  // lpart split
#define KSO  8                   // opart split

typedef __attribute__((ext_vector_type(4))) float floatx4;
typedef __attribute__((ext_vector_type(8))) short short8;
typedef __attribute__((ext_vector_type(2))) unsigned int uint2v;
typedef __fp16 h2raw __attribute__((ext_vector_type(2)));
typedef _Float16 h2 __attribute__((ext_vector_type(2)));

static __device__ __forceinline__ float bf2f(unsigned short u) {
  union { unsigned int i; float f; } x; x.i = ((unsigned int)u) << 16; return x.f;
}
static __device__ __forceinline__ unsigned short f2bf(float f) {
  union { float f; unsigned int i; } x; x.f = f;
  return (unsigned short)((x.i + 0x7fffu + ((x.i >> 16) & 1u)) >> 16);
}
static __device__ __forceinline__ unsigned int pkh2(float a, float b) {
  h2raw r = __builtin_amdgcn_cvt_pkrtz(a, b);
  union { h2raw h; unsigned int u; } x; x.h = r; return x.u;
}
static __device__ __forceinline__ h2 u2h(unsigned int u) {
  union { unsigned int u; h2 h; } x; x.u = u; return x.h;
}
static __device__ __forceinline__ unsigned int pkbf(float a, float b) {
  return (unsigned int)f2bf(a) | ((unsigned int)f2bf(b) << 16);
}

// ---------------------------------------------------------------------------
// K0: batched transpose+convert. z: 0,1=inp b0/b1 (512x1024 -> [s][c]);
// 2,3,4=Wq/Wk/Wv (512x1024 -> [n][c]); 5=Wo (1024x512 -> [co][j]). bf16 out.
// ---------------------------------------------------------------------------
__global__ __launch_bounds__(256) void ath_tr(
    const float* __restrict__ inp, const float* __restrict__ Wq,
    const float* __restrict__ Wk,  const float* __restrict__ Wv,
    const float* __restrict__ Wo,
    unsigned short* __restrict__ inpT, unsigned short* __restrict__ WT,
    unsigned short* __restrict__ WoT)
{
  const int z = blockIdx.z;
  const float* src; unsigned short* dst; int R, C;
  if      (z == 0) { src = inp;              dst = inpT;                R = 512;  C = 1024; }
  else if (z == 1) { src = inp + 512 * 1024; dst = inpT + 1024 * 512;   R = 512;  C = 1024; }
  else if (z == 2) { src = Wq;               dst = WT;                  R = 512;  C = 1024; }
  else if (z == 3) { src = Wk;               dst = WT + 1024 * 512;     R = 512;  C = 1024; }
  else if (z == 4) { src = Wv;               dst = WT + 2 * 1024 * 512; R = 512;  C = 1024; }
  else             { src = Wo;               dst = WoT;                 R = 1024; C = 512;  }
  const int ct = blockIdx.x, rt = blockIdx.y;
  if (ct * 32 >= C || rt * 32 >= R) return;

  __shared__ float Ts[32][33];
  const int t = threadIdx.x;
  {
    const int r = t >> 3, c4 = (t & 7) * 4;
    const floatx4 g = *(const floatx4*)(src + (size_t)(rt * 32 + r) * C + ct * 32 + c4);
    Ts[r][c4 + 0] = g[0]; Ts[r][c4 + 1] = g[1];
    Ts[r][c4 + 2] = g[2]; Ts[r][c4 + 3] = g[3];
  }
  __syncthreads();
  {
    const int i = t >> 3, k4 = (t & 7) * 4;
    const unsigned int o0 = pkbf(Ts[k4 + 0][i], Ts[k4 + 1][i]);
    const unsigned int o1 = pkbf(Ts[k4 + 2][i], Ts[k4 + 3][i]);
    *(uint2v*)(dst + (size_t)(ct * 32 + i) * R + rt * 32 + k4) = (uint2v){o0, o1};
  }
}

// ---------------------------------------------------------------------------
// K1: QKV projection from pre-transposed bf16 inputs.
// Q,K -> [b][h][s][d] ; V -> [b][v][d][s]. Staging = b128 row copies.
// ---------------------------------------------------------------------------
__global__ __launch_bounds__(256) void ath_qkv(
    const unsigned short* __restrict__ inpT,  // [b][s][c]
    const unsigned short* __restrict__ WT,    // [p][n][c]
    const float* __restrict__ Aq,
    const float* __restrict__ Ak,
    const float* __restrict__ Av,
    unsigned short* __restrict__ ws)
{
  const int sblk = blockIdx.x;
  const int nblk = blockIdx.y;
  const int z = blockIdx.z;
  const int b = z / 3, p = z % 3;
  const float* Ap = (p == 0) ? Aq : ((p == 1) ? Ak : Av);
  const float sig = 1.0f / (1.0f + __expf(-Ap[0]));

  __shared__ __align__(16) unsigned short As[64][40];
  __shared__ __align__(16) unsigned short Bs[64][40];

  const int tid = threadIdx.x;
  const int w = tid >> 6, lane = tid & 63;
  const int l15 = lane & 15, quad = lane >> 4;
  const int srow = tid >> 2, sc8 = (tid & 3) * 8;

  floatx4 acc[4];
#pragma unroll
  for (int i = 0; i < 4; ++i) acc[i] = (floatx4){0.f, 0.f, 0.f, 0.f};

  for (int cc = 0; cc < 16; ++cc) {
    const int c0 = cc * 32;
    __syncthreads();
    *(short8*)&As[srow][sc8] =
        *(const short8*)(inpT + ((size_t)(b * 1024 + sblk * 64 + srow)) * 512 + c0 + sc8);
    *(short8*)&Bs[srow][sc8] =
        *(const short8*)(WT + ((size_t)(p * 1024 + nblk * 64 + srow)) * 512 + c0 + sc8);
    __syncthreads();
    const short8 a = *(const short8*)&As[w * 16 + l15][quad * 8];
#pragma unroll
    for (int nt = 0; nt < 4; ++nt) {
      const short8 bb = *(const short8*)&Bs[nt * 16 + l15][quad * 8];
      acc[nt] = __builtin_amdgcn_mfma_f32_16x16x32_bf16(a, bb, acc[nt], 0, 0, 0);
    }
  }

  unsigned short* out = ws + (size_t)p * ((size_t)B_S * N_H * SEQL * D_K);
#pragma unroll
  for (int nt = 0; nt < 4; ++nt) {
    const int h = l15;
    const int d = nblk * 4 + nt;
#pragma unroll
    for (int r = 0; r < 4; ++r) {
      const int s = sblk * 64 + w * 16 + quad * 4 + r;
      const float vout = acc[nt][r] * sig;
      if (p == 2) out[((size_t)((b * N_H + h) * D_K + d)) * SEQL + s] = f2bf(vout);
      else        out[((size_t)((b * N_H + h) * SEQL + s)) * D_K + d] = f2bf(vout);
    }
  }
}

// ---------------------------------------------------------------------------
// K2a: partial l. grid(64 qblk, KSL, 2 b). Wave w owns k-tile w (16 k), all 16
// heads. J^T = mfma(K,Q). Chunk mask staged in LDS (64 floats).
// ---------------------------------------------------------------------------
__global__ __launch_bounds__(256, 4) void ath_lpart(
    const float* __restrict__ maskp,
    const float* __restrict__ Wl,
    const unsigned short* __restrict__ qkv,
    float* __restrict__ lp)
{
  const int qblk = blockIdx.x;
  const int ks   = blockIdx.y;
  const int b    = blockIdx.z;
  const int tid = threadIdx.x;
  const int w = tid >> 6, lane = tid & 63;
  const int l15 = lane & 15, quad = lane >> 4;

  const unsigned short* Qf = qkv;
  const unsigned short* Kf = qkv + (size_t)B_S * N_H * SEQL * D_K;

  __shared__ unsigned int JtU[4][2304];  // [k16][q16][hp8+pad1] f16 pairs, 36 KB
  __shared__ float Ms[64];

  if (tid < 64) Ms[tid] = maskp[b * SEQL + ks * 64 + tid];

  unsigned int WlTp[4][8];
#pragma unroll
  for (int gg = 0; gg < 4; ++gg)
#pragma unroll
    for (int hp = 0; hp < 8; ++hp)
      WlTp[gg][hp] = pkh2(Wl[(2 * hp) * 16 + quad * 4 + gg],
                          Wl[(2 * hp + 1) * 16 + quad * 4 + gg]);

  __syncthreads();  // Ms visible

  const int kabs0 = ks * 64 + w * 16;

#pragma unroll
  for (int hg = 0; hg < 2; ++hg) {
    floatx4 jc[8];
#pragma unroll
    for (int hh = 0; hh < 8; ++hh) {
      const int h = hg * 8 + hh;
      const unsigned short* qb = Qf + ((size_t)((b * N_H + h) * SEQL) + qblk * 16 + l15) * D_K;
      const unsigned short* kb = Kf + ((size_t)((b * N_H + h) * SEQL) + kabs0 + l15) * D_K;
      const short8 q0 = *(const short8*)(qb + quad * 8);
      const short8 q1 = *(const short8*)(qb + 32 + quad * 8);
      const short8 k0 = *(const short8*)(kb + quad * 8);
      const short8 k1 = *(const short8*)(kb + 32 + quad * 8);
      floatx4 c = (floatx4){0.f, 0.f, 0.f, 0.f};
      c = __builtin_amdgcn_mfma_f32_16x16x32_bf16(k0, q0, c, 0, 0, 0);  // A=K: rows k
      c = __builtin_amdgcn_mfma_f32_16x16x32_bf16(k1, q1, c, 0, 0, 0);
      jc[hh] = c;
    }
#pragma unroll
    for (int r = 0; r < 4; ++r) {
      const int base = ((quad * 4 + r) * 16 + l15) * 9 + hg * 4;
#pragma unroll
      for (int jj = 0; jj < 4; ++jj)
        JtU[w][base + jj] = pkh2(jc[2 * jj][r], jc[2 * jj + 1][r]);
    }
  }

  float l_acc[4] = {0.f, 0.f, 0.f, 0.f};
#pragma unroll 4
  for (int k = 0; k < 16; ++k) {
    const int jb = (k * 16 + l15) * 9;
    unsigned int ju[8];
#pragma unroll
    for (int hp = 0; hp < 8; ++hp) ju[hp] = JtU[w][jb + hp];
    const float m = Ms[w * 16 + k];
    h2 eh[4] = {(h2)(_Float16)0, (h2)(_Float16)0, (h2)(_Float16)0, (h2)(_Float16)0};
#pragma unroll
    for (int hp = 0; hp < 8; ++hp) {
      const h2 jv = u2h(ju[hp]);
      eh[0] += jv * u2h(WlTp[0][hp]);
      eh[1] += jv * u2h(WlTp[1][hp]);
      eh[2] += jv * u2h(WlTp[2][hp]);
      eh[3] += jv * u2h(WlTp[3][hp]);
    }
#pragma unroll
    for (int gg = 0; gg < 4; ++gg) {
      const float e = (float)eh[gg][0] + (float)eh[gg][1] - m;
      l_acc[gg] += __expf(fminf(fmaxf(e, -60.f), 60.f));
    }
  }

  __syncthreads();
  float* Ls = (float*)&JtU[0][0];
#pragma unroll
  for (int gg = 0; gg < 4; ++gg)
    Ls[w * 256 + l15 * 16 + quad * 4 + gg] = l_acc[gg];
  __syncthreads();
  {
    const float s = Ls[tid] + Ls[256 + tid] + Ls[512 + tid] + Ls[768 + tid];
    const int q = tid >> 4, g = tid & 15;
    lp[((size_t)((ks * 2 + b) * SEQL + qblk * 16 + q)) * 16 + g] = s;
  }
}

// ---------------------------------------------------------------------------
// K2r: invl = 1 / sum_ks lp. grid(128, 256 thr).
// ---------------------------------------------------------------------------
__global__ __launch_bounds__(256) void ath_linv(
    const float* __restrict__ lp, float* __restrict__ invl)
{
  const int t = blockIdx.x * 256 + threadIdx.x;
  const int b = t >> 14, rem = t & 16383;
  float s = 0.f;
#pragma unroll
  for (int ks = 0; ks < KSL; ++ks) s += lp[(size_t)((ks * 2 + b)) * 16384 + rem];
  invl[t] = 1.0f / fmaxf(s, 1e-37f);
}

// ---------------------------------------------------------------------------
// K2b: partial O. grid(64 qblk, KSO, 2 b). r10 core; chunk mask in LDS (128 f).
// ---------------------------------------------------------------------------
__global__ __launch_bounds__(256, 2) void ath_opart(
    const float* __restrict__ maskp,
    const float* __restrict__ Wl,
    const float* __restrict__ Ww,
    const unsigned short* __restrict__ qkv,
    const float* __restrict__ invl,
    unsigned short* __restrict__ Obp)
{
  const int qblk = blockIdx.x;
  const int ks   = blockIdx.y;
  const int b    = blockIdx.z;
  const int tid = threadIdx.x;
  const int w = tid >> 6, lane = tid & 63;
  const int l15 = lane & 15, quad = lane >> 4;

  const unsigned short* Qf = qkv;
  const unsigned short* Kf = qkv + (size_t)B_S * N_H * SEQL * D_K;
  const unsigned short* Vf = qkv + 2 * (size_t)B_S * N_H * SEQL * D_K;

  __shared__ unsigned int JtU[4][2304];       // per-wave J/P slice, 36 KB
  __shared__ unsigned int UsU[16 * 16 * 34];  // U bf16 [v16][q16][k64->34 uints], 34.8 KB
  __shared__ float invls[16][16];
  __shared__ float Ms[128];

  invls[tid >> 4][tid & 15] =
      invl[(size_t)b * 16384 + (qblk * 16 + (tid >> 4)) * 16 + (tid & 15)];
  if (tid < 128) Ms[tid] = maskp[b * SEQL + ks * 128 + tid];

  unsigned int WlTp[4][8], WwTp[4][8];
#pragma unroll
  for (int gg = 0; gg < 4; ++gg)
#pragma unroll
    for (int hp = 0; hp < 8; ++hp) {
      WlTp[gg][hp] = pkh2(Wl[(2 * hp) * 16 + quad * 4 + gg],
                          Wl[(2 * hp + 1) * 16 + quad * 4 + gg]);
      WwTp[gg][hp] = pkh2(Ww[(2 * hp) * 16 + quad * 4 + gg],
                          Ww[(2 * hp + 1) * 16 + quad * 4 + gg]);
    }

  float inv[4];
#pragma unroll
  for (int gg = 0; gg < 4; ++gg)
    inv[gg] = invl[(size_t)b * 16384 + (qblk * 16 + l15) * 16 + quad * 4 + gg];

  floatx4 oacc[4][4];
#pragma unroll
  for (int a = 0; a < 4; ++a)
#pragma unroll
    for (int d = 0; d < 4; ++d) oacc[a][d] = (floatx4){0.f, 0.f, 0.f, 0.f};

  __syncthreads();  // invls/Ms visible

  const int kchunk = SEQL / KSO;   // 128

  for (int rd = 0; rd < 2; ++rd) {
    const int kabs0 = ks * kchunk + (rd * 4 + w) * 16;

    // ---- J for all 16 heads (wave-private; rows k, cols q) ----
#pragma unroll
    for (int hg = 0; hg < 2; ++hg) {
      floatx4 jc[8];
#pragma unroll
      for (int hh = 0; hh < 8; ++hh) {
        const int h = hg * 8 + hh;
        const unsigned short* qb = Qf + ((size_t)((b * N_H + h) * SEQL) + qblk * 16 + l15) * D_K;
        const unsigned short* kb = Kf + ((size_t)((b * N_H + h) * SEQL) + kabs0 + l15) * D_K;
        const short8 q0 = *(const short8*)(qb + quad * 8);
        const short8 q1 = *(const short8*)(qb + 32 + quad * 8);
        const short8 k0 = *(const short8*)(kb + quad * 8);
        const short8 k1 = *(const short8*)(kb + 32 + quad * 8);
        floatx4 c = (floatx4){0.f, 0.f, 0.f, 0.f};
        c = __builtin_amdgcn_mfma_f32_16x16x32_bf16(k0, q0, c, 0, 0, 0);
        c = __builtin_amdgcn_mfma_f32_16x16x32_bf16(k1, q1, c, 0, 0, 0);
        jc[hh] = c;
      }
#pragma unroll
      for (int r = 0; r < 4; ++r) {
        const int base = ((quad * 4 + r) * 16 + l15) * 9 + hg * 4;
#pragma unroll
        for (int jj = 0; jj < 4; ++jj)
          JtU[w][base + jj] = pkh2(jc[2 * jj][r], jc[2 * jj + 1][r]);
      }
    }

    // ---- EL mix -> P f16 pairs, in-place over J (wave-lockstep-safe) ----
#pragma unroll 4
    for (int k = 0; k < 16; ++k) {
      const int jb = (k * 16 + l15) * 9;
      unsigned int ju[8];
#pragma unroll
      for (int hp = 0; hp < 8; ++hp) ju[hp] = JtU[w][jb + hp];
      const float m = Ms[(rd * 4 + w) * 16 + k];
      h2 eh[4] = {(h2)(_Float16)0, (h2)(_Float16)0, (h2)(_Float16)0, (h2)(_Float16)0};
#pragma unroll
      for (int hp = 0; hp < 8; ++hp) {
        const h2 jv = u2h(ju[hp]);
        eh[0] += jv * u2h(WlTp[0][hp]);
        eh[1] += jv * u2h(WlTp[1][hp]);
        eh[2] += jv * u2h(WlTp[2][hp]);
        eh[3] += jv * u2h(WlTp[3][hp]);
      }
      float p[4];
#pragma unroll
      for (int gg = 0; gg < 4; ++gg) {
        const float e = (float)eh[gg][0] + (float)eh[gg][1] - m;
        p[gg] = __expf(fminf(fmaxf(e, -60.f), 60.f)) * inv[gg];
      }
      JtU[w][jb + quad * 2 + 0] = pkh2(p[0], p[1]);
      JtU[w][jb + quad * 2 + 1] = pkh2(p[2], p[3]);
    }

    // ---- U mix: lane role q=l15, v=quad*4+vv -> Us bf16 [v][q][klocal] ----
#pragma unroll 4
    for (int kp = 0; kp < 8; ++kp) {
      float ue[4] = {0.f, 0.f, 0.f, 0.f}, uo[4] = {0.f, 0.f, 0.f, 0.f};
#pragma unroll
      for (int par = 0; par < 2; ++par) {
        const int jb = ((kp * 2 + par) * 16 + l15) * 9;
        unsigned int pu[8];
#pragma unroll
        for (int gp = 0; gp < 8; ++gp) pu[gp] = JtU[w][jb + gp];
        h2 uh[4] = {(h2)(_Float16)0, (h2)(_Float16)0, (h2)(_Float16)0, (h2)(_Float16)0};
#pragma unroll
        for (int gp = 0; gp < 8; ++gp) {
          const h2 pv = u2h(pu[gp]);
          uh[0] += pv * u2h(WwTp[0][gp]);
          uh[1] += pv * u2h(WwTp[1][gp]);
          uh[2] += pv * u2h(WwTp[2][gp]);
          uh[3] += pv * u2h(WwTp[3][gp]);
        }
        float* u = par ? uo : ue;
#pragma unroll
        for (int vv = 0; vv < 4; ++vv) u[vv] = (float)uh[vv][0] + (float)uh[vv][1];
      }
#pragma unroll
      for (int vv = 0; vv < 4; ++vv)
        UsU[((quad * 4 + vv) * 16 + l15) * 34 + w * 8 + kp] = pkbf(ue[vv], uo[vv]);
    }

    __syncthreads();  // all waves' Us slices ready

    // ---- V-phase: wave w -> v = 4w..4w+3; K=32 bf16 MFMA over 2 k-pairs ----
    const unsigned short* UsS = (const unsigned short*)UsU;
#pragma unroll
    for (int tp = 0; tp < 2; ++tp) {
      const int kt_abs = ks * kchunk + rd * 64 + tp * 32;
#pragma unroll
      for (int vv = 0; vv < 4; ++vv) {
        const int v = w * 4 + vv;
        const short8 ufr = *(const short8*)&UsS[((v * 16 + l15) * 34) * 2 + tp * 32 + quad * 8];
#pragma unroll
        for (int dt = 0; dt < 4; ++dt) {
          const short8 vfr = *(const short8*)(Vf +
              ((size_t)((b * N_H + v) * D_K + dt * 16 + l15)) * SEQL + kt_abs + quad * 8);
          oacc[vv][dt] = __builtin_amdgcn_mfma_f32_16x16x32_bf16(ufr, vfr, oacc[vv][dt], 0, 0, 0);
        }
      }
    }

    __syncthreads();  // Us free for next round
  }

#pragma unroll
  for (int vv = 0; vv < 4; ++vv) {
    const int v = w * 4 + vv;
#pragma unroll
    for (int dt = 0; dt < 4; ++dt) {
      const int d = dt * 16 + l15;
#pragma unroll
      for (int r = 0; r < 4; ++r) {
        const int q = qblk * 16 + quad * 4 + r;
        Obp[(size_t)ks * BQJ + ((size_t)(b * SEQL + q)) * 1024 + d * 16 + v] = f2bf(oacc[vv][dt][r]);
      }
    }
  }
}

// ---------------------------------------------------------------------------
// K2s: Obsum = sum_ks Obp. grid(1024, 256 thr).
// ---------------------------------------------------------------------------
__global__ __launch_bounds__(256) void ath_osum(
    const unsigned short* __restrict__ Obp,
    unsigned short* __restrict__ Obsum)
{
  const size_t i = ((size_t)blockIdx.x * 256 + threadIdx.x) * 8;
  float a[8];
#pragma unroll
  for (int e = 0; e < 8; ++e) a[e] = 0.f;
#pragma unroll
  for (int ks = 0; ks < KSO; ++ks) {
    const short8 v = *(const short8*)(Obp + (size_t)ks * BQJ + i);
#pragma unroll
    for (int e = 0; e < 8; ++e) a[e] += bf2f((unsigned short)v[e]);
  }
  short8 o;
#pragma unroll
  for (int e = 0; e < 8; ++e) o[e] = (short)f2bf(a[e]);
  *(short8*)(Obsum + i) = o;
}

// ---------------------------------------------------------------------------
// K3: out[b][co][q] = inp + sum_j Obsum[b][q][j] * WoT[co][j]. fp32 out.
// ---------------------------------------------------------------------------
__global__ __launch_bounds__(256) void ath_out(
    const float* __restrict__ inp,
    const unsigned short* __restrict__ WoT,   // [co][j] bf16
    const unsigned short* __restrict__ Ob,
    float* __restrict__ out)
{
  const int qblk = blockIdx.x;
  const int cblk = blockIdx.y;
  const int b    = blockIdx.z;
  const int tid = threadIdx.x;
  const int w = tid >> 6, lane = tid & 63;
  const int l15 = lane & 15, quad = lane >> 4;

  __shared__ __align__(16) unsigned short Os[64][40];
  __shared__ __align__(16) unsigned short Wt[64][40];

  floatx4 acc[4];
#pragma unroll
  for (int i = 0; i < 4; ++i) acc[i] = (floatx4){0.f, 0.f, 0.f, 0.f};

  const int srow = tid >> 2, sj8 = (tid & 3) * 8;

  for (int jc = 0; jc < 32; ++jc) {
    const int j0 = jc * 32;
    __syncthreads();
    *(short8*)&Os[srow][sj8] =
        *(const short8*)(Ob + ((size_t)(b * SEQL + qblk * 64 + srow)) * 1024 + j0 + sj8);
    *(short8*)&Wt[srow][sj8] =
        *(const short8*)(WoT + ((size_t)(cblk * 64 + srow)) * 1024 + j0 + sj8);
    __syncthreads();
    const short8 a = *(const short8*)&Os[w * 16 + l15][quad * 8];
#pragma unroll
    for (int nt = 0; nt < 4; ++nt) {
      const short8 bb = *(const short8*)&Wt[nt * 16 + l15][quad * 8];
      acc[nt] = __builtin_amdgcn_mfma_f32_16x16x32_bf16(a, bb, acc[nt], 0, 0, 0);
    }
  }

#pragma unroll
  for (int nt = 0; nt < 4; ++nt) {
    const int co = cblk * 64 + nt * 16 + l15;
    const int qb = qblk * 64 + w * 16 + quad * 4;
    const float* ip = inp + ((size_t)(b * 512 + co)) * SEQL + qb;
    float* op = out + ((size_t)(b * 512 + co)) * SEQL + qb;
#pragma unroll
    for (int r = 0; r < 4; ++r) op[r] = acc[nt][r] + ip[r];
  }
}

// ---------------------------------------------------------------------------
extern "C" void kernel_launch(void* const* d_in, const int* in_sizes, int n_in,
                              void* d_out, int out_size, void* d_ws, size_t ws_size,
                              hipStream_t stream) {
  (void)in_sizes; (void)n_in; (void)out_size; (void)ws_size;
  const float* inp   = (const float*)d_in[0];
  const float* maskp = (const float*)d_in[1];
  const float* Wq    = (const float*)d_in[2];
  const float* Wk    = (const float*)d_in[3];
  const float* Wv    = (const float*)d_in[4];
  const float* Aq    = (const float*)d_in[5];
  const float* Ak    = (const float*)d_in[6];
  const float* Av    = (const float*)d_in[7];
  const float* Wl    = (const float*)d_in[8];
  const float* Ww    = (const float*)d_in[9];
  const float* Wo    = (const float*)d_in[10];

  const size_t MB = 1u << 20;
  unsigned short* qkv   = (unsigned short*)d_ws;                       // [0,12) Q,K,V bf16
  unsigned short* Obsum = (unsigned short*)((char*)d_ws + 12 * MB);    // [12,16)
  float*          invl  = (float*)((char*)d_ws + 16 * MB);             // 128 KB
  unsigned short* WoT   = (unsigned short*)((char*)d_ws + 17 * MB);    // [17,18)
  float*          lp    = (float*)((char*)d_ws + 18 * MB);             // [18,20)
  unsigned short* WT    = (unsigned short*)((char*)d_ws + 20 * MB);    // [20,23)
  unsigned short* inpT  = (unsigned short*)((char*)d_ws + 23 * MB);    // [23,25)
  unsigned short* Obp   = (unsigned short*)((char*)d_ws + 18 * MB);    // [18,50)
  float* out = (float*)d_out;

  ath_tr<<<dim3(32, 32, 6), 256, 0, stream>>>(inp, Wq, Wk, Wv, Wo, inpT, WT, WoT);
  ath_qkv<<<dim3(16, 16, 6), 256, 0, stream>>>(inpT, WT, Aq, Ak, Av, qkv);
  ath_lpart<<<dim3(64, KSL, 2), 256, 0, stream>>>(maskp, Wl, qkv, lp);
  ath_linv<<<dim3(128), 256, 0, stream>>>(lp, invl);
  ath_opart<<<dim3(64, KSO, 2), 256, 0, stream>>>(maskp, Wl, Ww, qkv, invl, Obp);
  ath_osum<<<dim3(1024), 256, 0, stream>>>(Obp, Obsum);
  ath_out<<<dim3(16, 8, 2), 256, 0, stream>>>(inp, WoT, Obsum, out);
}